// Round 5
// baseline (268.023 us; speedup 1.0000x reference)
//
#include <hip/hip_runtime.h>
#include <hip/hip_bf16.h>
#include <math.h>

// Problem constants
#define BB   8
#define HI_  64
#define WI_  64
#define DD   128
#define HO_  32
#define WO_  32
#define NIN  4096
#define NOUT 1024
#define LN_EPS 1e-5f
#define ATT_EPS 1e-6f

typedef short bf16x8 __attribute__((ext_vector_type(8)));
typedef float f32x4  __attribute__((ext_vector_type(4)));

__device__ __forceinline__ ushort f2bf(float f) {
    union { float f; unsigned u; } a; a.f = f;
    unsigned u = a.u;
    return (ushort)((u + 0x7FFFu + ((u >> 16) & 1u)) >> 16);
}
__device__ __forceinline__ float bf2f(ushort u) {
    union { unsigned u; float f; } a; a.u = ((unsigned)u) << 16;
    return a.f;
}

// ---------------------------------------------------------------------------
// Weight conversion to bf16 (+ conv weight transpose to tap-major N x K).
// Layout: [wk 16384][wv 16384][wq 16384][w1 32768][w2 32768][wc 147456]
// ---------------------------------------------------------------------------
__global__ __launch_bounds__(256)
void wconvert_kernel(const float* __restrict__ wq, const float* __restrict__ wk,
                     const float* __restrict__ wv, const float* __restrict__ w1,
                     const float* __restrict__ w2, const float* __restrict__ sw,
                     ushort* __restrict__ dst)
{
    int i = blockIdx.x * 256 + threadIdx.x;   // total 262144
    float v;
    if (i < 16384)        v = wk[i];
    else if (i < 32768)   v = wv[i - 16384];
    else if (i < 49152)   v = wq[i - 32768];
    else if (i < 81920)   v = w1[i - 49152];
    else if (i < 114688)  v = w2[i - 81920];
    else {
        int j = i - 114688;
        int n = j / 1152;
        int rem = j - n * 1152;
        int tap = rem >> 7, di = rem & 127;
        v = sw[((size_t)(n * DD + di)) * 9 + tap];
    }
    dst[i] = f2bf(v);
}

// ---------------------------------------------------------------------------
// prep_kv: per 64-row block of x: LN(x) -> k GEMM, x -> v GEMM, write bf16
// kbuf/vbuf with unfold remap. K=128 single-shot. 4 waves (2M x 2N, 32x64).
// ---------------------------------------------------------------------------
__global__ __launch_bounds__(256)
void prep_kv_kernel(const float* __restrict__ x, const ushort* __restrict__ wkb,
                    const ushort* __restrict__ wvb,
                    const float* __restrict__ lg_, const float* __restrict__ lb_,
                    ushort* __restrict__ kbuf, ushort* __restrict__ vbuf)
{
    __shared__ float  xs[64][132];
    __shared__ ushort Aln[64][136];
    __shared__ ushort Araw[64][136];
    __shared__ ushort Bk[128][136];
    __shared__ ushort Bv[128][136];
    __shared__ float  rstat[64][2];
    const int tid = threadIdx.x;
    const int row0 = blockIdx.x * 64;

    #pragma unroll
    for (int i = 0; i < 8; ++i) {               // 2048 float4
        int l = tid + i * 256;
        int r = l >> 5, c4 = (l & 31) << 2;
        float4 v = *(const float4*)(x + (size_t)(row0 + r) * DD + c4);
        *(float4*)&xs[r][c4] = v;
        ushort4 o; o.x = f2bf(v.x); o.y = f2bf(v.y); o.z = f2bf(v.z); o.w = f2bf(v.w);
        *(ushort4*)&Araw[r][c4] = o;
    }
    __syncthreads();
    {   // row stats: 4 threads/row
        int r = tid >> 2, q = tid & 3;
        float s = 0.f, s2 = 0.f;
        #pragma unroll
        for (int c = 0; c < 32; ++c) { float v = xs[r][q * 32 + c]; s += v; s2 += v * v; }
        s += __shfl_down(s, 1, 64); s2 += __shfl_down(s2, 1, 64);
        s += __shfl_down(s, 2, 64); s2 += __shfl_down(s2, 2, 64);
        if (q == 0) {
            float mu = s * (1.f / DD);
            float var = s2 * (1.f / DD) - mu * mu;
            rstat[r][0] = mu; rstat[r][1] = rsqrtf(var + LN_EPS);
        }
    }
    __syncthreads();
    #pragma unroll
    for (int i = 0; i < 8; ++i) {               // build Aln
        int l = tid + i * 256;
        int r = l >> 5, c4 = (l & 31) << 2;
        float mu = rstat[r][0], rs = rstat[r][1];
        ushort4 o;
        o.x = f2bf((xs[r][c4 + 0] - mu) * rs * lg_[c4 + 0] + lb_[c4 + 0]);
        o.y = f2bf((xs[r][c4 + 1] - mu) * rs * lg_[c4 + 1] + lb_[c4 + 1]);
        o.z = f2bf((xs[r][c4 + 2] - mu) * rs * lg_[c4 + 2] + lb_[c4 + 2]);
        o.w = f2bf((xs[r][c4 + 3] - mu) * rs * lg_[c4 + 3] + lb_[c4 + 3]);
        *(ushort4*)&Aln[r][c4] = o;
    }
    #pragma unroll
    for (int i = 0; i < 8; ++i) {               // weights: 2048 uint4 each
        int l = tid + i * 256;
        int r = l >> 4, c8 = (l & 15) << 3;
        *(uint4*)&Bk[r][c8] = *(const uint4*)(wkb + (size_t)r * DD + c8);
        *(uint4*)&Bv[r][c8] = *(const uint4*)(wvb + (size_t)r * DD + c8);
    }
    __syncthreads();

    const int wid = tid >> 6, lane = tid & 63;
    const int wm = (wid & 1) * 32, wn = (wid >> 1) * 64;
    const int lr = lane & 15, lk = (lane >> 4) << 3;
    f32x4 ak[2][4] = {}, av[2][4] = {};
    #pragma unroll
    for (int ks = 0; ks < 4; ++ks) {
        int kk = ks * 32 + lk;
        bf16x8 aL[2], aR[2];
        #pragma unroll
        for (int mi = 0; mi < 2; ++mi) {
            aL[mi] = *(const bf16x8*)&Aln[wm + mi * 16 + lr][kk];
            aR[mi] = *(const bf16x8*)&Araw[wm + mi * 16 + lr][kk];
        }
        #pragma unroll
        for (int ni = 0; ni < 4; ++ni) {
            bf16x8 bK = *(const bf16x8*)&Bk[wn + ni * 16 + lr][kk];
            bf16x8 bV = *(const bf16x8*)&Bv[wn + ni * 16 + lr][kk];
            #pragma unroll
            for (int mi = 0; mi < 2; ++mi) {
                ak[mi][ni] = __builtin_amdgcn_mfma_f32_16x16x32_bf16(aL[mi], bK, ak[mi][ni], 0, 0, 0);
                av[mi][ni] = __builtin_amdgcn_mfma_f32_16x16x32_bf16(aR[mi], bV, av[mi][ni], 0, 0, 0);
            }
        }
    }
    #pragma unroll
    for (int mi = 0; mi < 2; ++mi) {
        #pragma unroll
        for (int ni = 0; ni < 4; ++ni) {
            int n = wn + ni * 16 + (lane & 15);
            #pragma unroll
            for (int r = 0; r < 4; ++r) {
                int m = row0 + wm + mi * 16 + ((lane >> 4) << 2) + r;
                int b = m >> 12, pix = m & 4095;
                int iy = pix >> 6, ix = pix & 63;
                int h = ((iy & 1) << 1) | (ix & 1);
                int cp = ((iy >> 1) << 5) | (ix >> 1);
                size_t orow = ((size_t)(b * 4 + h) << 10) + cp;
                kbuf[orow * DD + n] = f2bf(ak[mi][ni][r]);
                vbuf[orow * DD + n] = f2bf(av[mi][ni][r]);
            }
        }
    }
}

// ---------------------------------------------------------------------------
// conv GEMM (im2col gather, K=1152) + LN epilogue -> xout fp32.
// ---------------------------------------------------------------------------
__global__ __launch_bounds__(256)
void conv_ln_kernel(const float* __restrict__ x, const ushort* __restrict__ wcb,
                    const float* __restrict__ lg_, const float* __restrict__ lb_,
                    float* __restrict__ xout)
{
    __shared__ ushort As[64][72];
    __shared__ ushort Bs[128][72];
    __shared__ float  es[64][132];
    __shared__ float  rstat[64][2];
    const int tid = threadIdx.x, wid = tid >> 6, lane = tid & 63;
    const int row0 = blockIdx.x * 64;
    const int wm = (wid & 1) * 32, wn = (wid >> 1) * 64;
    const int lr = lane & 15, lk = (lane >> 4) << 3;
    f32x4 acc[2][4] = {};

    for (int k0 = 0; k0 < 1152; k0 += 64) {
        #pragma unroll
        for (int i = 0; i < 4; ++i) {           // A gather: 1024 float4
            int l = tid + i * 256;
            int r = l >> 4, c4 = (l & 15) << 2;
            int m = row0 + r;
            int b = m >> 10, p = m & 1023;
            int y = p >> 5, xx = p & 31;
            int kg = k0 + c4;
            int tap = kg >> 7, di = kg & 127;
            int ky = tap / 3, kx = tap - ky * 3;
            int iy = 2 * y + ky - 1, ix = 2 * xx + kx - 1;
            float4 v;
            if ((unsigned)iy < (unsigned)HI_ && (unsigned)ix < (unsigned)WI_)
                v = *(const float4*)(x + ((size_t)b * NIN + iy * WI_ + ix) * DD + di);
            else v = make_float4(0.f, 0.f, 0.f, 0.f);
            ushort4 o; o.x = f2bf(v.x); o.y = f2bf(v.y); o.z = f2bf(v.z); o.w = f2bf(v.w);
            *(ushort4*)&As[r][c4] = o;
        }
        #pragma unroll
        for (int i = 0; i < 4; ++i) {           // B: 1024 uint4
            int l = tid + i * 256;
            int r = l >> 3, c8 = (l & 7) << 3;
            *(uint4*)&Bs[r][c8] = *(const uint4*)(wcb + (size_t)r * 1152 + k0 + c8);
        }
        __syncthreads();
        #pragma unroll
        for (int ks = 0; ks < 2; ++ks) {
            int kk = ks * 32 + lk;
            bf16x8 aF[2];
            aF[0] = *(const bf16x8*)&As[wm + lr][kk];
            aF[1] = *(const bf16x8*)&As[wm + 16 + lr][kk];
            #pragma unroll
            for (int ni = 0; ni < 4; ++ni) {
                bf16x8 bF = *(const bf16x8*)&Bs[wn + ni * 16 + lr][kk];
                acc[0][ni] = __builtin_amdgcn_mfma_f32_16x16x32_bf16(aF[0], bF, acc[0][ni], 0, 0, 0);
                acc[1][ni] = __builtin_amdgcn_mfma_f32_16x16x32_bf16(aF[1], bF, acc[1][ni], 0, 0, 0);
            }
        }
        __syncthreads();
    }
    #pragma unroll
    for (int mi = 0; mi < 2; ++mi)
        #pragma unroll
        for (int ni = 0; ni < 4; ++ni) {
            int n = wn + ni * 16 + (lane & 15);
            #pragma unroll
            for (int r = 0; r < 4; ++r)
                es[wm + mi * 16 + ((lane >> 4) << 2) + r][n] = acc[mi][ni][r];
        }
    __syncthreads();
    {   // row stats
        int r = tid >> 2, q = tid & 3;
        float s = 0.f, s2 = 0.f;
        #pragma unroll
        for (int c = 0; c < 32; ++c) { float v = es[r][q * 32 + c]; s += v; s2 += v * v; }
        s += __shfl_down(s, 1, 64); s2 += __shfl_down(s2, 1, 64);
        s += __shfl_down(s, 2, 64); s2 += __shfl_down(s2, 2, 64);
        if (q == 0) {
            float mu = s * (1.f / DD);
            float var = s2 * (1.f / DD) - mu * mu;
            rstat[r][0] = mu; rstat[r][1] = rsqrtf(var + LN_EPS);
        }
    }
    __syncthreads();
    #pragma unroll
    for (int i = 0; i < 8; ++i) {
        int l = tid + i * 256;
        int r = l >> 5, c4 = (l & 31) << 2;
        float mu = rstat[r][0], rs = rstat[r][1];
        float4 o;
        o.x = (es[r][c4 + 0] - mu) * rs * lg_[c4 + 0] + lb_[c4 + 0];
        o.y = (es[r][c4 + 1] - mu) * rs * lg_[c4 + 1] + lb_[c4 + 1];
        o.z = (es[r][c4 + 2] - mu) * rs * lg_[c4 + 2] + lb_[c4 + 2];
        o.w = (es[r][c4 + 3] - mu) * rs * lg_[c4 + 3] + lb_[c4 + 3];
        *(float4*)(xout + (size_t)(row0 + r) * DD + c4) = o;
    }
}

// ---------------------------------------------------------------------------
// Fused iteration kernel (see header comment above layout macros).
// ---------------------------------------------------------------------------
#define OFF_QS    17424
#define OFF_R0    30480
#define OFF_K0S   134928
#define OFF_LG    144144
#define OFF_LG0   148752
#define OFF_SM0   148912
#define OFF_DEN   148928
#define OFF_HSUM  149056
#define OFF_RSTAT 149568
#define SMEM_SZ   149952
#define OFF_AQ    OFF_R0
#define OFF_BQ    43536
#define OFF_W1    OFF_R0
#define OFF_A1    100112
#define OFF_H1    117008
#define OFF_W2    OFF_R0
#define OFF_ES    100112

template<int LAST>
__global__ __launch_bounds__(256)
void iter_kernel(float* __restrict__ xout, const ushort* __restrict__ kbuf,
                 const ushort* __restrict__ vbuf, const ushort* __restrict__ wqb,
                 const ushort* __restrict__ w1b, const ushort* __restrict__ w2b,
                 const float* __restrict__ b1, const float* __restrict__ b2,
                 const float* __restrict__ lg_, const float* __restrict__ lb_,
                 const float* __restrict__ rpb, const float* __restrict__ tau,
                 float* __restrict__ gbuf, float* __restrict__ denb,
                 float* __restrict__ out)
{
    const int bcy = blockIdx.x;
    const int b = bcy >> 5, cy = bcy & 31;
    const int ry0 = min(max(cy - 1, 0), HO_ - 3);
    const int tid = threadIdx.x;
    const int wid = tid >> 6, lane = tid & 63;
    const int lr = lane & 15, lk = (lane >> 4) << 3;

    __shared__ __align__(16) char smem[SMEM_SZ];
    float  (*xsf)[132]  = (float  (*)[132])(smem);
    ushort (*qs)[136]   = (ushort (*)[136])(smem + OFF_QS);
    float  (*rstat)[2]  = (float  (*)[2])(smem + OFF_RSTAT);
    ushort (*Aq)[136]   = (ushort (*)[136])(smem + OFF_AQ);
    ushort (*Bq)[136]   = (ushort (*)[136])(smem + OFF_BQ);
    ushort* kvp         = (ushort*)(smem + OFF_R0);
    ushort (*k0s)[128]  = (ushort (*)[128])(smem + OFF_K0S);
    float*  lgp         = (float*)(smem + OFF_LG);
    float*  lg0         = (float*)(smem + OFF_LG0);
    float*  sm0         = (float*)(smem + OFF_SM0);
    float*  den         = (float*)(smem + OFF_DEN);
    float  (*hsum)[4]   = (float  (*)[4])(smem + OFF_HSUM);
    ushort (*W1)[136]   = (ushort (*)[136])(smem + OFF_W1);
    ushort (*A1)[136]   = (ushort (*)[136])(smem + OFF_A1);
    ushort (*h1s)[264]  = (ushort (*)[264])(smem + OFF_H1);
    ushort (*W2)[264]   = (ushort (*)[264])(smem + OFF_W2);
    float  (*es)[132]   = (float  (*)[132])(smem + OFF_ES);

    // ---- P0: load xout tile rows 0..31 + row 32 = (b, p=0); wq -> LDS ----
    for (int l = tid; l < 1056; l += 256) {
        int r = l >> 5, c4 = (l & 31) << 2;
        int g = b * NOUT + (r < 32 ? cy * 32 + r : 0);
        *(float4*)&xsf[r][c4] = *(const float4*)(xout + (size_t)g * DD + c4);
    }
    #pragma unroll
    for (int i = 0; i < 8; ++i) {
        int l = tid + i * 256;
        int r = l >> 4, c8 = (l & 15) << 3;
        *(uint4*)&Bq[r][c8] = *(const uint4*)(wqb + (size_t)r * DD + c8);
    }
    __syncthreads();
    if (tid < 132) {
        int r = tid >> 2, q = tid & 3;
        float s = 0.f, s2 = 0.f;
        #pragma unroll
        for (int c = 0; c < 32; ++c) { float v = xsf[r][q * 32 + c]; s += v; s2 += v * v; }
        s += __shfl_down(s, 1, 64); s2 += __shfl_down(s2, 1, 64);
        s += __shfl_down(s, 2, 64); s2 += __shfl_down(s2, 2, 64);
        if (q == 0) {
            float mu = s * (1.f / DD);
            float var = s2 * (1.f / DD) - mu * mu;
            rstat[r][0] = mu; rstat[r][1] = rsqrtf(var + LN_EPS);
        }
    }
    __syncthreads();
    for (int l = tid; l < 1056; l += 256) {
        int r = l >> 5, c4 = (l & 31) << 2;
        float mu = rstat[r][0], rs = rstat[r][1];
        ushort4 o;
        o.x = f2bf((xsf[r][c4 + 0] - mu) * rs * lg_[c4 + 0] + lb_[c4 + 0]);
        o.y = f2bf((xsf[r][c4 + 1] - mu) * rs * lg_[c4 + 1] + lb_[c4 + 1]);
        o.z = f2bf((xsf[r][c4 + 2] - mu) * rs * lg_[c4 + 2] + lb_[c4 + 2]);
        o.w = f2bf((xsf[r][c4 + 3] - mu) * rs * lg_[c4 + 3] + lb_[c4 + 3]);
        *(ushort4*)&Aq[r][c4] = o;
    }
    for (int l = tid; l < 480; l += 256) {
        int r = 33 + (l >> 5), c4 = (l & 31) << 2;
        ushort4 z; z.x = 0; z.y = 0; z.z = 0; z.w = 0;
        *(ushort4*)&Aq[r][c4] = z;
    }
    __syncthreads();

    // ---- P1: q GEMM (M=48, N=128, K=128) -> qs ----
    {
        const int wn = wid * 32;
        f32x4 acc[3][2] = {};
        #pragma unroll
        for (int ks = 0; ks < 4; ++ks) {
            int kk = ks * 32 + lk;
            bf16x8 aF[3];
            #pragma unroll
            for (int mi = 0; mi < 3; ++mi) aF[mi] = *(const bf16x8*)&Aq[mi * 16 + lr][kk];
            #pragma unroll
            for (int ni = 0; ni < 2; ++ni) {
                bf16x8 bF = *(const bf16x8*)&Bq[wn + ni * 16 + lr][kk];
                #pragma unroll
                for (int mi = 0; mi < 3; ++mi)
                    acc[mi][ni] = __builtin_amdgcn_mfma_f32_16x16x32_bf16(aF[mi], bF, acc[mi][ni], 0, 0, 0);
            }
        }
        #pragma unroll
        for (int mi = 0; mi < 3; ++mi)
            #pragma unroll
            for (int ni = 0; ni < 2; ++ni) {
                int n = wn + ni * 16 + (lane & 15);
                #pragma unroll
                for (int r = 0; r < 4; ++r) {
                    int m = mi * 16 + ((lane >> 4) << 2) + r;
                    qs[m][n] = f2bf(acc[mi][ni][r]);
                }
            }
    }
    __syncthreads();

    // ---- P2: attention ----
    #pragma unroll
    for (int i = 0; i < 24; ++i) {               // K tile
        int l = tid + i * 256;
        int h = l / 1536, l2 = l - h * 1536;
        int rc = l2 >> 4, d8 = (l2 & 15) << 3;
        int r = rc >> 5, c = rc & 31;
        *(uint4*)(kvp + ((h * 3 + r) * 32 + c) * 136 + d8) =
            *(const uint4*)(kbuf + (((size_t)(b * 4 + h) << 10) + (ry0 + r) * 32 + c) * DD + d8);
    }
    for (int l = tid; l < 576; l += 256) {       // p=0 window k rows
        int row = l >> 4, d8 = (l & 15) << 3;
        int h = row / 9, jj = row - h * 9;
        int ky = jj / 3, kx = jj - ky * 3;
        *(uint4*)&k0s[h * 9 + jj][d8] =
            *(const uint4*)(kbuf + (((size_t)(b * 4 + h) << 10) + ky * 32 + kx) * DD + d8);
    }
    __syncthreads();

    for (int task = tid; task < 1188; task += 256) {
        const ushort *kp, *qp;
        int c = 0, h, jj;
        if (task < 1152) {
            c = task / 36; int t2 = task - c * 36;
            h = t2 / 9; jj = t2 - h * 9;
            int ky = jj / 3, kx = jj - ky * 3;
            int nx = min(max(c - 1, 0), WO_ - 3) + kx;
            kp = kvp + ((h * 3 + ky) * 32 + nx) * 136; qp = &qs[c][0];
        } else {
            int t2 = task - 1152;
            h = t2 / 9; jj = t2 - h * 9;
            kp = &k0s[h * 9 + jj][0]; qp = &qs[32][0];
        }
        float s = 0.f;
        #pragma unroll 4
        for (int d = 0; d < 128; d += 8) {
            uint4 ku = *(const uint4*)(kp + d);
            uint4 qu = *(const uint4*)(qp + d);
            const ushort* kk2 = (const ushort*)&ku;
            const ushort* qq2 = (const ushort*)&qu;
            #pragma unroll
            for (int t = 0; t < 8; ++t) s += bf2f(kk2[t]) * bf2f(qq2[t]);
        }
        if (task < 1152) lgp[c * 36 + h * 9 + jj] = s;
        else             lg0[task - 1152] = s;
    }
    __syncthreads();

    if (tid < 132) {                              // softmax (+EPS)
        float scale = expf(tau[0]);
        int h; const float* lptr; int c = 0;
        if (tid < 128) { c = tid >> 2; h = tid & 3; lptr = &lgp[c * 36 + h * 9]; }
        else           { h = tid - 128; lptr = &lg0[h * 9]; }
        float tmpv[9], mx = -1e30f;
        #pragma unroll
        for (int jj = 0; jj < 9; ++jj) {
            float v = (lptr[jj] + rpb[h * 9 + jj]) * scale;
            tmpv[jj] = v; mx = fmaxf(mx, v);
        }
        float ss = 0.f;
        #pragma unroll
        for (int jj = 0; jj < 9; ++jj) { tmpv[jj] = expf(tmpv[jj] - mx); ss += tmpv[jj]; }
        float inv = 1.f / ss;
        if (tid < 128) {
            #pragma unroll
            for (int jj = 0; jj < 9; ++jj) lgp[c * 36 + h * 9 + jj] = tmpv[jj] * inv + ATT_EPS;
        } else sm0[h] = tmpv[0] * inv + ATT_EPS;
    }
    __syncthreads();

    if (tid < 128) {                              // gather -> gbuf, head-sums
        int c = tid >> 2, h = tid & 3;
        float s = 0.f, gv[9];
        #pragma unroll
        for (int jj = 0; jj < 9; ++jj) {
            int dy = jj / 3 - 1, dx = jj % 3 - 1;
            bool valid = ((unsigned)(cy + dy) < (unsigned)HO_) && ((unsigned)(c + dx) < (unsigned)WO_);
            float v = valid ? lgp[c * 36 + h * 9 + jj] : sm0[h];
            gv[jj] = v; s += v;
        }
        float* gp = gbuf + (((size_t)(b * 4 + h) << 10) + cy * 32 + c) * 9;
        #pragma unroll
        for (int jj = 0; jj < 9; ++jj) { gp[jj] = gv[jj]; lgp[c * 36 + h * 9 + jj] = gv[jj]; }
        hsum[c][h] = s;
    }
    __syncthreads();
    if (tid < 32) {
        float dd = 4.f * (hsum[tid][0] + hsum[tid][1] + hsum[tid][2] + hsum[tid][3]) + ATT_EPS;
        den[tid] = 1.f / dd;
        denb[b * NOUT + cy * 32 + tid] = dd;
    }
    __syncthreads();
    if (tid < 128) {
        int c = tid >> 2, h = tid & 3;
        float inv = den[c];
        #pragma unroll
        for (int jj = 0; jj < 9; ++jj) lgp[c * 36 + h * 9 + jj] *= inv;
    }
    __syncthreads();

    #pragma unroll
    for (int i = 0; i < 24; ++i) {               // V tile over K tile
        int l = tid + i * 256;
        int h = l / 1536, l2 = l - h * 1536;
        int rc = l2 >> 4, d8 = (l2 & 15) << 3;
        int r = rc >> 5, c = rc & 31;
        *(uint4*)(kvp + ((h * 3 + r) * 32 + c) * 136 + d8) =
            *(const uint4*)(vbuf + (((size_t)(b * 4 + h) << 10) + (ry0 + r) * 32 + c) * DD + d8);
    }
    __syncthreads();

    {   // AV update into xsf
        int c = tid >> 3, d0 = (tid & 7) << 4;
        int rx0 = min(max(c - 1, 0), WO_ - 3);
        float acc[16] = {};
        #pragma unroll
        for (int h = 0; h < 4; ++h)
            #pragma unroll
            for (int jj = 0; jj < 9; ++jj) {
                float cf = lgp[c * 36 + h * 9 + jj];
                int ky = jj / 3, kx = jj - ky * 3;
                const ushort* vp = kvp + ((h * 3 + ky) * 32 + rx0 + kx) * 136 + d0;
                uint4 v0 = *(const uint4*)(vp);
                uint4 v1 = *(const uint4*)(vp + 8);
                const ushort* vs0 = (const ushort*)&v0;
                const ushort* vs1 = (const ushort*)&v1;
                #pragma unroll
                for (int t = 0; t < 8; ++t) {
                    acc[t]     += cf * bf2f(vs0[t]);
                    acc[t + 8] += cf * bf2f(vs1[t]);
                }
            }
        #pragma unroll
        for (int t = 0; t < 16; t += 4) {
            float4 o = *(float4*)&xsf[c][d0 + t];
            o.x += acc[t]; o.y += acc[t + 1]; o.z += acc[t + 2]; o.w += acc[t + 3];
            *(float4*)&xsf[c][d0 + t] = o;
        }
    }
    __syncthreads();

    // ---- P3: FFN1 ----
    for (int l = tid; l < 1024; l += 256) {
        int r = l >> 5, c4 = (l & 31) << 2;
        ushort4 o;
        o.x = f2bf(xsf[r][c4 + 0]); o.y = f2bf(xsf[r][c4 + 1]);
        o.z = f2bf(xsf[r][c4 + 2]); o.w = f2bf(xsf[r][c4 + 3]);
        *(ushort4*)&A1[r][c4] = o;
    }
    #pragma unroll
    for (int i = 0; i < 16; ++i) {
        int l = tid + i * 256;
        int r = l >> 4, c8 = (l & 15) << 3;
        *(uint4*)&W1[r][c8] = *(const uint4*)(w1b + (size_t)r * DD + c8);
    }
    __syncthreads();
    {
        const int wn = wid * 64;
        f32x4 acc[2][4] = {};
        #pragma unroll
        for (int ks = 0; ks < 4; ++ks) {
            int kk = ks * 32 + lk;
            bf16x8 aF[2];
            aF[0] = *(const bf16x8*)&A1[lr][kk];
            aF[1] = *(const bf16x8*)&A1[16 + lr][kk];
            #pragma unroll
            for (int ni = 0; ni < 4; ++ni) {
                bf16x8 bF = *(const bf16x8*)&W1[wn + ni * 16 + lr][kk];
                acc[0][ni] = __builtin_amdgcn_mfma_f32_16x16x32_bf16(aF[0], bF, acc[0][ni], 0, 0, 0);
                acc[1][ni] = __builtin_amdgcn_mfma_f32_16x16x32_bf16(aF[1], bF, acc[1][ni], 0, 0, 0);
            }
        }
        #pragma unroll
        for (int mi = 0; mi < 2; ++mi)
            #pragma unroll
            for (int ni = 0; ni < 4; ++ni) {
                int n = wn + ni * 16 + (lane & 15);
                float bv = b1[n];
                #pragma unroll
                for (int r = 0; r < 4; ++r) {
                    int m = mi * 16 + ((lane >> 4) << 2) + r;
                    float v = acc[mi][ni][r] + bv;
                    v = 0.5f * v * (1.f + erff(v * 0.70710678118654752f));
                    h1s[m][n] = f2bf(v);
                }
            }
    }
    __syncthreads();

    // ---- P4: FFN2 + LN + residual -> xout (+out) ----
    #pragma unroll
    for (int i = 0; i < 16; ++i) {
        int l = tid + i * 256;
        int r = l >> 5, c8 = (l & 31) << 3;
        *(uint4*)&W2[r][c8] = *(const uint4*)(w2b + (size_t)r * 256 + c8);
    }
    __syncthreads();
    {
        const int wn = wid * 32;
        f32x4 acc[2][2] = {};
        #pragma unroll
        for (int ks = 0; ks < 8; ++ks) {
            int kk = ks * 32 + lk;
            bf16x8 aF[2];
            aF[0] = *(const bf16x8*)&h1s[lr][kk];
            aF[1] = *(const bf16x8*)&h1s[16 + lr][kk];
            #pragma unroll
            for (int ni = 0; ni < 2; ++ni) {
                bf16x8 bF = *(const bf16x8*)&W2[wn + ni * 16 + lr][kk];
                acc[0][ni] = __builtin_amdgcn_mfma_f32_16x16x32_bf16(aF[0], bF, acc[0][ni], 0, 0, 0);
                acc[1][ni] = __builtin_amdgcn_mfma_f32_16x16x32_bf16(aF[1], bF, acc[1][ni], 0, 0, 0);
            }
        }
        #pragma unroll
        for (int mi = 0; mi < 2; ++mi)
            #pragma unroll
            for (int ni = 0; ni < 2; ++ni) {
                int n = wn + ni * 16 + (lane & 15);
                float bv = b2[n];
                #pragma unroll
                for (int r = 0; r < 4; ++r)
                    es[mi * 16 + ((lane >> 4) << 2) + r][n] = acc[mi][ni][r] + bv;
            }
    }
    __syncthreads();
    {   // LN stats: 8 threads/row
        int r = tid >> 3, qq = tid & 7;
        float s = 0.f, s2 = 0.f;
        #pragma unroll
        for (int c = 0; c < 16; ++c) { float v = es[r][qq * 16 + c]; s += v; s2 += v * v; }
        s += __shfl_down(s, 1, 64); s2 += __shfl_down(s2, 1, 64);
        s += __shfl_down(s, 2, 64); s2 += __shfl_down(s2, 2, 64);
        s += __shfl_down(s, 4, 64); s2 += __shfl_down(s2, 4, 64);
        if (qq == 0) {
            float mu = s * (1.f / DD);
            float var = s2 * (1.f / DD) - mu * mu;
            rstat[r][0] = mu; rstat[r][1] = rsqrtf(var + LN_EPS);
        }
    }
    __syncthreads();
    for (int l = tid; l < 1024; l += 256) {
        int r = l >> 5, c4 = (l & 31) << 2;
        float mu = rstat[r][0], rs = rstat[r][1];
        size_t off = ((size_t)(b * NOUT + cy * 32 + r)) * DD + c4;
        float4 o;
        o.x = xsf[r][c4 + 0] + (es[r][c4 + 0] - mu) * rs * lg_[c4 + 0] + lb_[c4 + 0];
        o.y = xsf[r][c4 + 1] + (es[r][c4 + 1] - mu) * rs * lg_[c4 + 1] + lb_[c4 + 1];
        o.z = xsf[r][c4 + 2] + (es[r][c4 + 2] - mu) * rs * lg_[c4 + 2] + lb_[c4 + 2];
        o.w = xsf[r][c4 + 3] + (es[r][c4 + 3] - mu) * rs * lg_[c4 + 3] + lb_[c4 + 3];
        *(float4*)(xout + off) = o;
        if (LAST) *(float4*)(out + off) = o;
    }
}

// ---------------------------------------------------------------------------
// A_row (blocks 0..32767) and A_col incl. dump (blocks 32768..65535).
// ---------------------------------------------------------------------------
__global__ __launch_bounds__(256)
void arowcol_kernel(const float* __restrict__ gbuf, const float* __restrict__ denb,
                    float* __restrict__ Arow, float* __restrict__ Acol)
{
    const int tid = threadIdx.x;
    __shared__ int   cols[9];
    __shared__ float vals[9];
    __shared__ float wred[9][4];
    if (blockIdx.x < 32768) {
        const int bi = blockIdx.x;
        const int b = bi >> 12, i = bi & 4095;
        const int h = i >> 10, p = i & 1023;
        const int cy = p >> 5, cx = p & 31;
        if (tid < 9) {
            int dy = tid / 3 - 1, dx = tid % 3 - 1;
            bool valid = ((unsigned)(cy + dy) < (unsigned)HO_) && ((unsigned)(cx + dx) < (unsigned)WO_);
            cols[tid] = valid ? (cy + dy) * WO_ + (cx + dx) : 0;
            vals[tid] = 4.f * gbuf[(((size_t)(b * 4 + h) << 10) + p) * 9 + tid];
        }
        __syncthreads();
        float* row = Arow + (size_t)bi * NOUT;
        #pragma unroll
        for (int cc = 0; cc < 4; ++cc) {
            int c = cc * 256 + tid;
            float acc = 0.f;
            #pragma unroll
            for (int jj = 0; jj < 9; ++jj)
                if (cols[jj] == c) acc += vals[jj];
            row[c] = acc;
        }
    } else {
        const int br = blockIdx.x - 32768;
        const int b = br >> 12, r = br & 4095;
        const int h = r & 3, coarse = r >> 2;
        const int cy = coarse >> 5, cx = coarse & 31;
        if (tid < 9) {
            int dy = tid / 3 - 1, dx = tid % 3 - 1;
            int py = cy - dy, px = cx - dx;
            float v = 0.f;
            if ((unsigned)py < (unsigned)HO_ && (unsigned)px < (unsigned)WO_) {
                int p = py * WO_ + px;
                v = gbuf[(((size_t)(b * 4 + h) << 10) + p) * 9 + tid] / denb[b * NOUT + p];
            }
            vals[tid] = v;
        }
        if (r == 0) {
            float part[9] = {};
            for (int p = tid; p < NOUT; p += 256) {
                float invd = 1.f / denb[b * NOUT + p];
                int py = p >> 5, px = p & 31;
                #pragma unroll
                for (int jj = 0; jj < 9; ++jj) {
                    int dy = jj / 3 - 1, dx = jj % 3 - 1;
                    bool valid = ((unsigned)(py + dy) < (unsigned)HO_) && ((unsigned)(px + dx) < (unsigned)WO_);
                    if (!valid) part[jj] += invd;
                }
            }
            #pragma unroll
            for (int jj = 0; jj < 9; ++jj) {
                float s = part[jj];
                #pragma unroll
                for (int o = 32; o > 0; o >>= 1) s += __shfl_down(s, o, 64);
                if ((tid & 63) == 0) wred[jj][tid >> 6] = s;
            }
            __syncthreads();
            if (tid < 9) {
                float s = wred[tid][0] + wred[tid][1] + wred[tid][2] + wred[tid][3];
                float H = 0.f;
                for (int h2 = 0; h2 < 4; ++h2)
                    H += gbuf[(((size_t)(b * 4 + h2)) << 10) * 9];
                vals[tid] += H * s;
            }
        }
        __syncthreads();
        float* row = Acol + (size_t)br * NOUT;
        #pragma unroll
        for (int cc = 0; cc < 4; ++cc) {
            int c = cc * 256 + tid;
            row[c] = (c < 36) ? vals[c % 9] : 0.f;
        }
    }
}

// ---------------------------------------------------------------------------
extern "C" void kernel_launch(void* const* d_in, const int* in_sizes, int n_in,
                              void* d_out, int out_size, void* d_ws, size_t ws_size,
                              hipStream_t stream)
{
    const float* x        = (const float*)d_in[0];
    const float* seed_w   = (const float*)d_in[1];
    const float* wq       = (const float*)d_in[2];
    const float* wk       = (const float*)d_in[3];
    const float* wv       = (const float*)d_in[4];
    const float* w1       = (const float*)d_in[5];
    const float* b1       = (const float*)d_in[6];
    const float* w2       = (const float*)d_in[7];
    const float* b2       = (const float*)d_in[8];
    const float* ln_in_g  = (const float*)d_in[9];
    const float* ln_in_b  = (const float*)d_in[10];
    const float* ln_out_g = (const float*)d_in[11];
    const float* ln_out_b = (const float*)d_in[12];
    const float* rpb      = (const float*)d_in[13];
    const float* tau      = (const float*)d_in[14];

    float* out  = (float*)d_out;
    float* Arow = out + (size_t)BB * NOUT * DD;
    float* Acol = Arow + (size_t)BB * NIN * NOUT;

    // Must-survive scratch in d_ws:
    float* ws    = (float*)d_ws;
    float* xout  = ws;                                 // 1,048,576
    float* gbuf  = xout + (size_t)BB * NOUT * DD;      // 294,912
    float* denb  = gbuf + (size_t)BB * 4 * NOUT * 9;   // 8,192
    ushort* wb   = (ushort*)(denb + BB * NOUT);        // 262,144 ushorts
    ushort* wkb  = wb;
    ushort* wvb  = wb + 16384;
    ushort* wqb  = wb + 32768;
    ushort* w1b  = wb + 49152;
    ushort* w2b  = wb + 81920;
    ushort* wcb  = wb + 114688;

    // Dead-by-the-end scratch carved from the A_row output region:
    ushort* kbuf = (ushort*)Arow;                       // 4,194,304 ushorts
    ushort* vbuf = kbuf + (size_t)4194304;              // 4,194,304 ushorts

    // --- preamble ---
    wconvert_kernel<<<1024, 256, 0, stream>>>(wq, wk, wv, w1, w2, seed_w, wb);
    prep_kv_kernel<<<BB * NIN / 64, 256, 0, stream>>>(x, wkb, wvb, ln_in_g, ln_in_b,
                                                      kbuf, vbuf);
    conv_ln_kernel<<<BB * NOUT / 64, 256, 0, stream>>>(x, wcb, ln_out_g, ln_out_b, xout);

    // --- 3 fused iterations ---
    for (int it = 0; it < 3; ++it) {
        if (it < 2)
            iter_kernel<0><<<BB * HO_, 256, 0, stream>>>(xout, kbuf, vbuf, wqb, w1b, w2b,
                                                         b1, b2, ln_out_g, ln_out_b, rpb,
                                                         tau, gbuf, denb, out);
        else
            iter_kernel<1><<<BB * HO_, 256, 0, stream>>>(xout, kbuf, vbuf, wqb, w1b, w2b,
                                                         b1, b2, ln_out_g, ln_out_b, rpb,
                                                         tau, gbuf, denb, out);
    }

    // --- epilogue: A_row + A_col (+dump inline) ---
    arowcol_kernel<<<2 * BB * NIN, 256, 0, stream>>>(gbuf, denb, Arow, Acol);
}

// Round 6
// 223.729 us; speedup vs baseline: 1.1980x; 1.1980x over previous
//
#include <hip/hip_runtime.h>
#include <hip/hip_bf16.h>
#include <math.h>

// Problem constants
#define BB   8
#define HI_  64
#define WI_  64
#define DD   128
#define HO_  32
#define WO_  32
#define NIN  4096
#define NOUT 1024
#define LN_EPS 1e-5f
#define ATT_EPS 1e-6f

typedef short bf16x8 __attribute__((ext_vector_type(8)));
typedef float f32x4  __attribute__((ext_vector_type(4)));

__device__ __forceinline__ ushort f2bf(float f) {
    union { float f; unsigned u; } a; a.f = f;
    unsigned u = a.u;
    return (ushort)((u + 0x7FFFu + ((u >> 16) & 1u)) >> 16);
}
__device__ __forceinline__ float bf2f(ushort u) {
    union { unsigned u; float f; } a; a.u = ((unsigned)u) << 16;
    return a.f;
}

// ---------------------------------------------------------------------------
// Weight conversion to bf16 (+ conv weight transpose to tap-major N x K).
// Layout: [wk 16384][wv 16384][wq 16384][w1 32768][w2 32768][wc 147456]
// ---------------------------------------------------------------------------
__global__ __launch_bounds__(256)
void wconvert_kernel(const float* __restrict__ wq, const float* __restrict__ wk,
                     const float* __restrict__ wv, const float* __restrict__ w1,
                     const float* __restrict__ w2, const float* __restrict__ sw,
                     ushort* __restrict__ dst)
{
    int i = blockIdx.x * 256 + threadIdx.x;   // total 262144
    float v;
    if (i < 16384)        v = wk[i];
    else if (i < 32768)   v = wv[i - 16384];
    else if (i < 49152)   v = wq[i - 32768];
    else if (i < 81920)   v = w1[i - 49152];
    else if (i < 114688)  v = w2[i - 81920];
    else {
        int j = i - 114688;
        int n = j / 1152;
        int rem = j - n * 1152;
        int tap = rem >> 7, di = rem & 127;
        v = sw[((size_t)(n * DD + di)) * 9 + tap];
    }
    dst[i] = f2bf(v);
}

// ---------------------------------------------------------------------------
// prep_kv: per 64-row block of x: LN(x) -> k GEMM, x -> v GEMM, write bf16
// kbuf/vbuf with unfold remap. (unchanged from round 4)
// ---------------------------------------------------------------------------
__global__ __launch_bounds__(256)
void prep_kv_kernel(const float* __restrict__ x, const ushort* __restrict__ wkb,
                    const ushort* __restrict__ wvb,
                    const float* __restrict__ lg_, const float* __restrict__ lb_,
                    ushort* __restrict__ kbuf, ushort* __restrict__ vbuf)
{
    __shared__ float  xs[64][132];
    __shared__ ushort Aln[64][136];
    __shared__ ushort Araw[64][136];
    __shared__ ushort Bk[128][136];
    __shared__ ushort Bv[128][136];
    __shared__ float  rstat[64][2];
    const int tid = threadIdx.x;
    const int row0 = blockIdx.x * 64;

    #pragma unroll
    for (int i = 0; i < 8; ++i) {
        int l = tid + i * 256;
        int r = l >> 5, c4 = (l & 31) << 2;
        float4 v = *(const float4*)(x + (size_t)(row0 + r) * DD + c4);
        *(float4*)&xs[r][c4] = v;
        ushort4 o; o.x = f2bf(v.x); o.y = f2bf(v.y); o.z = f2bf(v.z); o.w = f2bf(v.w);
        *(ushort4*)&Araw[r][c4] = o;
    }
    __syncthreads();
    {
        int r = tid >> 2, q = tid & 3;
        float s = 0.f, s2 = 0.f;
        #pragma unroll
        for (int c = 0; c < 32; ++c) { float v = xs[r][q * 32 + c]; s += v; s2 += v * v; }
        s += __shfl_down(s, 1, 64); s2 += __shfl_down(s2, 1, 64);
        s += __shfl_down(s, 2, 64); s2 += __shfl_down(s2, 2, 64);
        if (q == 0) {
            float mu = s * (1.f / DD);
            float var = s2 * (1.f / DD) - mu * mu;
            rstat[r][0] = mu; rstat[r][1] = rsqrtf(var + LN_EPS);
        }
    }
    __syncthreads();
    #pragma unroll
    for (int i = 0; i < 8; ++i) {
        int l = tid + i * 256;
        int r = l >> 5, c4 = (l & 31) << 2;
        float mu = rstat[r][0], rs = rstat[r][1];
        ushort4 o;
        o.x = f2bf((xs[r][c4 + 0] - mu) * rs * lg_[c4 + 0] + lb_[c4 + 0]);
        o.y = f2bf((xs[r][c4 + 1] - mu) * rs * lg_[c4 + 1] + lb_[c4 + 1]);
        o.z = f2bf((xs[r][c4 + 2] - mu) * rs * lg_[c4 + 2] + lb_[c4 + 2]);
        o.w = f2bf((xs[r][c4 + 3] - mu) * rs * lg_[c4 + 3] + lb_[c4 + 3]);
        *(ushort4*)&Aln[r][c4] = o;
    }
    #pragma unroll
    for (int i = 0; i < 8; ++i) {
        int l = tid + i * 256;
        int r = l >> 4, c8 = (l & 15) << 3;
        *(uint4*)&Bk[r][c8] = *(const uint4*)(wkb + (size_t)r * DD + c8);
        *(uint4*)&Bv[r][c8] = *(const uint4*)(wvb + (size_t)r * DD + c8);
    }
    __syncthreads();

    const int wid = tid >> 6, lane = tid & 63;
    const int wm = (wid & 1) * 32, wn = (wid >> 1) * 64;
    const int lr = lane & 15, lk = (lane >> 4) << 3;
    f32x4 ak[2][4] = {}, av[2][4] = {};
    #pragma unroll
    for (int ks = 0; ks < 4; ++ks) {
        int kk = ks * 32 + lk;
        bf16x8 aL[2], aR[2];
        #pragma unroll
        for (int mi = 0; mi < 2; ++mi) {
            aL[mi] = *(const bf16x8*)&Aln[wm + mi * 16 + lr][kk];
            aR[mi] = *(const bf16x8*)&Araw[wm + mi * 16 + lr][kk];
        }
        #pragma unroll
        for (int ni = 0; ni < 4; ++ni) {
            bf16x8 bK = *(const bf16x8*)&Bk[wn + ni * 16 + lr][kk];
            bf16x8 bV = *(const bf16x8*)&Bv[wn + ni * 16 + lr][kk];
            #pragma unroll
            for (int mi = 0; mi < 2; ++mi) {
                ak[mi][ni] = __builtin_amdgcn_mfma_f32_16x16x32_bf16(aL[mi], bK, ak[mi][ni], 0, 0, 0);
                av[mi][ni] = __builtin_amdgcn_mfma_f32_16x16x32_bf16(aR[mi], bV, av[mi][ni], 0, 0, 0);
            }
        }
    }
    #pragma unroll
    for (int mi = 0; mi < 2; ++mi) {
        #pragma unroll
        for (int ni = 0; ni < 4; ++ni) {
            int n = wn + ni * 16 + (lane & 15);
            #pragma unroll
            for (int r = 0; r < 4; ++r) {
                int m = row0 + wm + mi * 16 + ((lane >> 4) << 2) + r;
                int b = m >> 12, pix = m & 4095;
                int iy = pix >> 6, ix = pix & 63;
                int h = ((iy & 1) << 1) | (ix & 1);
                int cp = ((iy >> 1) << 5) | (ix >> 1);
                size_t orow = ((size_t)(b * 4 + h) << 10) + cp;
                kbuf[orow * DD + n] = f2bf(ak[mi][ni][r]);
                vbuf[orow * DD + n] = f2bf(av[mi][ni][r]);
            }
        }
    }
}

// ---------------------------------------------------------------------------
// conv GEMM (im2col gather, K=1152) + LN epilogue -> xout fp32. (unchanged)
// ---------------------------------------------------------------------------
__global__ __launch_bounds__(256)
void conv_ln_kernel(const float* __restrict__ x, const ushort* __restrict__ wcb,
                    const float* __restrict__ lg_, const float* __restrict__ lb_,
                    float* __restrict__ xout)
{
    __shared__ ushort As[64][72];
    __shared__ ushort Bs[128][72];
    __shared__ float  es[64][132];
    __shared__ float  rstat[64][2];
    const int tid = threadIdx.x, wid = tid >> 6, lane = tid & 63;
    const int row0 = blockIdx.x * 64;
    const int wm = (wid & 1) * 32, wn = (wid >> 1) * 64;
    const int lr = lane & 15, lk = (lane >> 4) << 3;
    f32x4 acc[2][4] = {};

    for (int k0 = 0; k0 < 1152; k0 += 64) {
        #pragma unroll
        for (int i = 0; i < 4; ++i) {
            int l = tid + i * 256;
            int r = l >> 4, c4 = (l & 15) << 2;
            int m = row0 + r;
            int b = m >> 10, p = m & 1023;
            int y = p >> 5, xx = p & 31;
            int kg = k0 + c4;
            int tap = kg >> 7, di = kg & 127;
            int ky = tap / 3, kx = tap - ky * 3;
            int iy = 2 * y + ky - 1, ix = 2 * xx + kx - 1;
            float4 v;
            if ((unsigned)iy < (unsigned)HI_ && (unsigned)ix < (unsigned)WI_)
                v = *(const float4*)(x + ((size_t)b * NIN + iy * WI_ + ix) * DD + di);
            else v = make_float4(0.f, 0.f, 0.f, 0.f);
            ushort4 o; o.x = f2bf(v.x); o.y = f2bf(v.y); o.z = f2bf(v.z); o.w = f2bf(v.w);
            *(ushort4*)&As[r][c4] = o;
        }
        #pragma unroll
        for (int i = 0; i < 4; ++i) {
            int l = tid + i * 256;
            int r = l >> 3, c8 = (l & 7) << 3;
            *(uint4*)&Bs[r][c8] = *(const uint4*)(wcb + (size_t)r * 1152 + k0 + c8);
        }
        __syncthreads();
        #pragma unroll
        for (int ks = 0; ks < 2; ++ks) {
            int kk = ks * 32 + lk;
            bf16x8 aF[2];
            aF[0] = *(const bf16x8*)&As[wm + lr][kk];
            aF[1] = *(const bf16x8*)&As[wm + 16 + lr][kk];
            #pragma unroll
            for (int ni = 0; ni < 4; ++ni) {
                bf16x8 bF = *(const bf16x8*)&Bs[wn + ni * 16 + lr][kk];
                acc[0][ni] = __builtin_amdgcn_mfma_f32_16x16x32_bf16(aF[0], bF, acc[0][ni], 0, 0, 0);
                acc[1][ni] = __builtin_amdgcn_mfma_f32_16x16x32_bf16(aF[1], bF, acc[1][ni], 0, 0, 0);
            }
        }
        __syncthreads();
    }
    #pragma unroll
    for (int mi = 0; mi < 2; ++mi)
        #pragma unroll
        for (int ni = 0; ni < 4; ++ni) {
            int n = wn + ni * 16 + (lane & 15);
            #pragma unroll
            for (int r = 0; r < 4; ++r)
                es[wm + mi * 16 + ((lane >> 4) << 2) + r][n] = acc[mi][ni][r];
        }
    __syncthreads();
    {
        int r = tid >> 2, q = tid & 3;
        float s = 0.f, s2 = 0.f;
        #pragma unroll
        for (int c = 0; c < 32; ++c) { float v = es[r][q * 32 + c]; s += v; s2 += v * v; }
        s += __shfl_down(s, 1, 64); s2 += __shfl_down(s2, 1, 64);
        s += __shfl_down(s, 2, 64); s2 += __shfl_down(s2, 2, 64);
        if (q == 0) {
            float mu = s * (1.f / DD);
            float var = s2 * (1.f / DD) - mu * mu;
            rstat[r][0] = mu; rstat[r][1] = rsqrtf(var + LN_EPS);
        }
    }
    __syncthreads();
    #pragma unroll
    for (int i = 0; i < 8; ++i) {
        int l = tid + i * 256;
        int r = l >> 5, c4 = (l & 31) << 2;
        float mu = rstat[r][0], rs = rstat[r][1];
        float4 o;
        o.x = (es[r][c4 + 0] - mu) * rs * lg_[c4 + 0] + lb_[c4 + 0];
        o.y = (es[r][c4 + 1] - mu) * rs * lg_[c4 + 1] + lb_[c4 + 1];
        o.z = (es[r][c4 + 2] - mu) * rs * lg_[c4 + 2] + lb_[c4 + 2];
        o.w = (es[r][c4 + 3] - mu) * rs * lg_[c4 + 3] + lb_[c4 + 3];
        *(float4*)(xout + (size_t)(row0 + r) * DD + c4) = o;
    }
}

// ---------------------------------------------------------------------------
// attnq: merged LN + q-GEMM (direct wq fragments) + attention + AV update.
// One block per (b,cy). Writes gbuf, denb, updated xout tile.
// LDS arena: Aq (during q GEMM) is overlaid by the k/v tile (after barrier).
// ---------------------------------------------------------------------------
#define OFF_QS    17424
#define OFF_ARENA 30480
#define OFF_K0S   134928
#define OFF_LG    144144
#define OFF_LG0   148752
#define OFF_SM0   148912
#define OFF_DEN   148928
#define OFF_HSUM  149056
#define OFF_RSTAT 149568
#define SMEM_SZ   149952

__global__ __launch_bounds__(256)
void attnq_kernel(float* __restrict__ xout, const ushort* __restrict__ kbuf,
                  const ushort* __restrict__ vbuf, const ushort* __restrict__ wqb,
                  const float* __restrict__ lg_, const float* __restrict__ lb_,
                  const float* __restrict__ rpb, const float* __restrict__ tau,
                  float* __restrict__ gbuf, float* __restrict__ denb)
{
    const int bcy = blockIdx.x;
    const int b = bcy >> 5, cy = bcy & 31;
    const int ry0 = min(max(cy - 1, 0), HO_ - 3);
    const int tid = threadIdx.x;
    const int wid = tid >> 6, lane = tid & 63;
    const int lr = lane & 15, lk = (lane >> 4) << 3;

    __shared__ __align__(16) char smem[SMEM_SZ];
    float  (*xsf)[132]  = (float  (*)[132])(smem);            // [33][132]
    ushort (*qs)[136]   = (ushort (*)[136])(smem + OFF_QS);   // [48][136]
    ushort (*Aq)[136]   = (ushort (*)[136])(smem + OFF_ARENA);// [48][136] (phase 0/1)
    ushort* kvp         = (ushort*)(smem + OFF_ARENA);        // [4][3][32][136] (phase 2+)
    ushort (*k0s)[128]  = (ushort (*)[128])(smem + OFF_K0S);  // [36][128]
    float*  lgp         = (float*)(smem + OFF_LG);            // [32][36]
    float*  lg0         = (float*)(smem + OFF_LG0);           // [36]
    float*  sm0         = (float*)(smem + OFF_SM0);           // [4]
    float*  den         = (float*)(smem + OFF_DEN);           // [32]
    float  (*hsum)[4]   = (float  (*)[4])(smem + OFF_HSUM);   // [32][4]
    float  (*rstat)[2]  = (float  (*)[2])(smem + OFF_RSTAT);  // [48][2]

    // ---- P0: xout tile rows 0..31 + row 32 = (b, p=0); LN -> Aq ----
    for (int l = tid; l < 1056; l += 256) {
        int r = l >> 5, c4 = (l & 31) << 2;
        int g = b * NOUT + (r < 32 ? cy * 32 + r : 0);
        *(float4*)&xsf[r][c4] = *(const float4*)(xout + (size_t)g * DD + c4);
    }
    __syncthreads();
    if (tid < 132) {
        int r = tid >> 2, q = tid & 3;
        float s = 0.f, s2 = 0.f;
        #pragma unroll
        for (int c = 0; c < 32; ++c) { float v = xsf[r][q * 32 + c]; s += v; s2 += v * v; }
        s += __shfl_down(s, 1, 64); s2 += __shfl_down(s2, 1, 64);
        s += __shfl_down(s, 2, 64); s2 += __shfl_down(s2, 2, 64);
        if (q == 0) {
            float mu = s * (1.f / DD);
            float var = s2 * (1.f / DD) - mu * mu;
            rstat[r][0] = mu; rstat[r][1] = rsqrtf(var + LN_EPS);
        }
    }
    __syncthreads();
    for (int l = tid; l < 1056; l += 256) {
        int r = l >> 5, c4 = (l & 31) << 2;
        float mu = rstat[r][0], rs = rstat[r][1];
        ushort4 o;
        o.x = f2bf((xsf[r][c4 + 0] - mu) * rs * lg_[c4 + 0] + lb_[c4 + 0]);
        o.y = f2bf((xsf[r][c4 + 1] - mu) * rs * lg_[c4 + 1] + lb_[c4 + 1]);
        o.z = f2bf((xsf[r][c4 + 2] - mu) * rs * lg_[c4 + 2] + lb_[c4 + 2]);
        o.w = f2bf((xsf[r][c4 + 3] - mu) * rs * lg_[c4 + 3] + lb_[c4 + 3]);
        *(ushort4*)&Aq[r][c4] = o;
    }
    for (int l = tid; l < 480; l += 256) {
        int r = 33 + (l >> 5), c4 = (l & 31) << 2;
        ushort4 z; z.x = 0; z.y = 0; z.z = 0; z.w = 0;
        *(ushort4*)&Aq[r][c4] = z;
    }
    __syncthreads();

    // ---- P1: q GEMM (M=48, N=128, K=128), wq fragments direct from global ----
    {
        const int wn = wid * 32;
        f32x4 acc[3][2] = {};
        #pragma unroll
        for (int ks = 0; ks < 4; ++ks) {
            int kk = ks * 32 + lk;
            bf16x8 aF[3];
            #pragma unroll
            for (int mi = 0; mi < 3; ++mi) aF[mi] = *(const bf16x8*)&Aq[mi * 16 + lr][kk];
            #pragma unroll
            for (int ni = 0; ni < 2; ++ni) {
                bf16x8 bF = *(const bf16x8*)(wqb + (size_t)(wn + ni * 16 + lr) * DD + kk);
                #pragma unroll
                for (int mi = 0; mi < 3; ++mi)
                    acc[mi][ni] = __builtin_amdgcn_mfma_f32_16x16x32_bf16(aF[mi], bF, acc[mi][ni], 0, 0, 0);
            }
        }
        #pragma unroll
        for (int mi = 0; mi < 3; ++mi)
            #pragma unroll
            for (int ni = 0; ni < 2; ++ni) {
                int n = wn + ni * 16 + (lane & 15);
                #pragma unroll
                for (int r = 0; r < 4; ++r) {
                    int m = mi * 16 + ((lane >> 4) << 2) + r;
                    qs[m][n] = f2bf(acc[mi][ni][r]);
                }
            }
    }
    __syncthreads();   // Aq reads done; arena can be overlaid with k/v

    // ---- P2: attention ----
    #pragma unroll
    for (int i = 0; i < 24; ++i) {               // K tile: 6144 uint4
        int l = tid + i * 256;
        int h = l / 1536, l2 = l - h * 1536;
        int rc = l2 >> 4, d8 = (l2 & 15) << 3;
        int r = rc >> 5, c = rc & 31;
        *(uint4*)(kvp + ((h * 3 + r) * 32 + c) * 136 + d8) =
            *(const uint4*)(kbuf + (((size_t)(b * 4 + h) << 10) + (ry0 + r) * 32 + c) * DD + d8);
    }
    for (int l = tid; l < 576; l += 256) {       // p=0 window k rows
        int row = l >> 4, d8 = (l & 15) << 3;
        int h = row / 9, jj = row - h * 9;
        int ky = jj / 3, kx = jj - ky * 3;
        *(uint4*)&k0s[h * 9 + jj][d8] =
            *(const uint4*)(kbuf + (((size_t)(b * 4 + h) << 10) + ky * 32 + kx) * DD + d8);
    }
    __syncthreads();

    for (int task = tid; task < 1188; task += 256) {
        const ushort *kp, *qp;
        int c = 0, h, jj;
        if (task < 1152) {
            c = task / 36; int t2 = task - c * 36;
            h = t2 / 9; jj = t2 - h * 9;
            int ky = jj / 3, kx = jj - ky * 3;
            int nx = min(max(c - 1, 0), WO_ - 3) + kx;
            kp = kvp + ((h * 3 + ky) * 32 + nx) * 136; qp = &qs[c][0];
        } else {
            int t2 = task - 1152;
            h = t2 / 9; jj = t2 - h * 9;
            kp = &k0s[h * 9 + jj][0]; qp = &qs[32][0];
        }
        float s = 0.f;
        #pragma unroll 4
        for (int d = 0; d < 128; d += 8) {
            uint4 ku = *(const uint4*)(kp + d);
            uint4 qu = *(const uint4*)(qp + d);
            const ushort* kk2 = (const ushort*)&ku;
            const ushort* qq2 = (const ushort*)&qu;
            #pragma unroll
            for (int t = 0; t < 8; ++t) s += bf2f(kk2[t]) * bf2f(qq2[t]);
        }
        if (task < 1152) lgp[c * 36 + h * 9 + jj] = s;
        else             lg0[task - 1152] = s;
    }
    __syncthreads();

    if (tid < 132) {                              // softmax (+EPS)
        float scale = expf(tau[0]);
        int h; const float* lptr; int c = 0;
        if (tid < 128) { c = tid >> 2; h = tid & 3; lptr = &lgp[c * 36 + h * 9]; }
        else           { h = tid - 128; lptr = &lg0[h * 9]; }
        float tmpv[9], mx = -1e30f;
        #pragma unroll
        for (int jj = 0; jj < 9; ++jj) {
            float v = (lptr[jj] + rpb[h * 9 + jj]) * scale;
            tmpv[jj] = v; mx = fmaxf(mx, v);
        }
        float ss = 0.f;
        #pragma unroll
        for (int jj = 0; jj < 9; ++jj) { tmpv[jj] = expf(tmpv[jj] - mx); ss += tmpv[jj]; }
        float inv = 1.f / ss;
        if (tid < 128) {
            #pragma unroll
            for (int jj = 0; jj < 9; ++jj) lgp[c * 36 + h * 9 + jj] = tmpv[jj] * inv + ATT_EPS;
        } else sm0[h] = tmpv[0] * inv + ATT_EPS;
    }
    __syncthreads();

    if (tid < 128) {                              // gather -> gbuf, head-sums
        int c = tid >> 2, h = tid & 3;
        float s = 0.f, gv[9];
        #pragma unroll
        for (int jj = 0; jj < 9; ++jj) {
            int dy = jj / 3 - 1, dx = jj % 3 - 1;
            bool valid = ((unsigned)(cy + dy) < (unsigned)HO_) && ((unsigned)(c + dx) < (unsigned)WO_);
            float v = valid ? lgp[c * 36 + h * 9 + jj] : sm0[h];
            gv[jj] = v; s += v;
        }
        float* gp = gbuf + (((size_t)(b * 4 + h) << 10) + cy * 32 + c) * 9;
        #pragma unroll
        for (int jj = 0; jj < 9; ++jj) { gp[jj] = gv[jj]; lgp[c * 36 + h * 9 + jj] = gv[jj]; }
        hsum[c][h] = s;
    }
    __syncthreads();
    if (tid < 32) {
        float dd = 4.f * (hsum[tid][0] + hsum[tid][1] + hsum[tid][2] + hsum[tid][3]) + ATT_EPS;
        den[tid] = 1.f / dd;
        denb[b * NOUT + cy * 32 + tid] = dd;
    }
    __syncthreads();
    if (tid < 128) {
        int c = tid >> 2, h = tid & 3;
        float inv = den[c];
        #pragma unroll
        for (int jj = 0; jj < 9; ++jj) lgp[c * 36 + h * 9 + jj] *= inv;
    }
    __syncthreads();

    #pragma unroll
    for (int i = 0; i < 24; ++i) {               // V tile over K tile
        int l = tid + i * 256;
        int h = l / 1536, l2 = l - h * 1536;
        int rc = l2 >> 4, d8 = (l2 & 15) << 3;
        int r = rc >> 5, c = rc & 31;
        *(uint4*)(kvp + ((h * 3 + r) * 32 + c) * 136 + d8) =
            *(const uint4*)(vbuf + (((size_t)(b * 4 + h) << 10) + (ry0 + r) * 32 + c) * DD + d8);
    }
    __syncthreads();

    {   // AV update into xsf
        int c = tid >> 3, d0 = (tid & 7) << 4;
        int rx0 = min(max(c - 1, 0), WO_ - 3);
        float acc[16] = {};
        #pragma unroll
        for (int h = 0; h < 4; ++h)
            #pragma unroll
            for (int jj = 0; jj < 9; ++jj) {
                float cf = lgp[c * 36 + h * 9 + jj];
                int ky = jj / 3, kx = jj - ky * 3;
                const ushort* vp = kvp + ((h * 3 + ky) * 32 + rx0 + kx) * 136 + d0;
                uint4 v0 = *(const uint4*)(vp);
                uint4 v1 = *(const uint4*)(vp + 8);
                const ushort* vs0 = (const ushort*)&v0;
                const ushort* vs1 = (const ushort*)&v1;
                #pragma unroll
                for (int t = 0; t < 8; ++t) {
                    acc[t]     += cf * bf2f(vs0[t]);
                    acc[t + 8] += cf * bf2f(vs1[t]);
                }
            }
        #pragma unroll
        for (int t = 0; t < 16; t += 4) {
            float4 o = *(float4*)&xsf[c][d0 + t];
            o.x += acc[t]; o.y += acc[t + 1]; o.z += acc[t + 2]; o.w += acc[t + 3];
            *(float4*)&xsf[c][d0 + t] = o;
        }
    }
    __syncthreads();

    // write updated tile to xout
    for (int l = tid; l < 1024; l += 256) {
        int r = l >> 5, c4 = (l & 31) << 2;
        *(float4*)(xout + ((size_t)(b * NOUT + cy * 32 + r)) * DD + c4) = *(float4*)&xsf[r][c4];
    }
}

// ---------------------------------------------------------------------------
// FFN1: h1 = gelu(xout @ w1^T + b1), bf16 out. 16-row tiles (512 blocks),
// W1 fragments direct from global (no LDS staging).
// ---------------------------------------------------------------------------
__global__ __launch_bounds__(256)
void ffn1_kernel(const float* __restrict__ xout, const ushort* __restrict__ w1b,
                 const float* __restrict__ b1, ushort* __restrict__ h1)
{
    __shared__ ushort A1[16][136];
    const int tid = threadIdx.x, wid = tid >> 6, lane = tid & 63;
    const int row0 = blockIdx.x * 16;
    const int wn = wid * 64;
    const int lr = lane & 15, lk = (lane >> 4) << 3;

    #pragma unroll
    for (int i = 0; i < 2; ++i) {               // A: 512 float4
        int l = tid + i * 256;
        int r = l >> 5, c4 = (l & 31) << 2;
        float4 v = *(const float4*)(xout + (size_t)(row0 + r) * DD + c4);
        ushort4 o; o.x = f2bf(v.x); o.y = f2bf(v.y); o.z = f2bf(v.z); o.w = f2bf(v.w);
        *(ushort4*)&A1[r][c4] = o;
    }
    __syncthreads();
    f32x4 acc[4] = {};
    #pragma unroll
    for (int ks = 0; ks < 4; ++ks) {
        int kk = ks * 32 + lk;
        bf16x8 a0 = *(const bf16x8*)&A1[lr][kk];
        #pragma unroll
        for (int ni = 0; ni < 4; ++ni) {
            bf16x8 bF = *(const bf16x8*)(w1b + (size_t)(wn + ni * 16 + lr) * DD + kk);
            acc[ni] = __builtin_amdgcn_mfma_f32_16x16x32_bf16(a0, bF, acc[ni], 0, 0, 0);
        }
    }
    #pragma unroll
    for (int ni = 0; ni < 4; ++ni) {
        int n = wn + ni * 16 + (lane & 15);
        float bv = b1[n];
        #pragma unroll
        for (int r = 0; r < 4; ++r) {
            int m = row0 + ((lane >> 4) << 2) + r;
            float v = acc[ni][r] + bv;
            v = 0.5f * v * (1.f + erff(v * 0.70710678118654752f));
            h1[(size_t)m * 256 + n] = f2bf(v);
        }
    }
}

// ---------------------------------------------------------------------------
// FFN2: xout += LN(h1 @ w2^T + b2). 16-row tiles (512 blocks), W2 fragments
// direct from global. LAST also writes final x_out to d_out.
// ---------------------------------------------------------------------------
template<int LAST>
__global__ __launch_bounds__(256)
void ffn2_kernel(const ushort* __restrict__ h1, const ushort* __restrict__ w2b,
                 const float* __restrict__ b2, const float* __restrict__ lg_,
                 const float* __restrict__ lb_, float* __restrict__ xout,
                 float* __restrict__ out)
{
    __shared__ ushort A2[16][264];
    __shared__ float  es[16][132];
    __shared__ float  rstat[16][2];
    const int tid = threadIdx.x, wid = tid >> 6, lane = tid & 63;
    const int row0 = blockIdx.x * 16;
    const int wn = wid * 32;
    const int lr = lane & 15, lk = (lane >> 4) << 3;

    #pragma unroll
    for (int i = 0; i < 2; ++i) {               // A: 512 uint4
        int l = tid + i * 256;
        int r = l >> 5, c8 = (l & 31) << 3;
        *(uint4*)&A2[r][c8] = *(const uint4*)(h1 + (size_t)(row0 + r) * 256 + c8);
    }
    __syncthreads();
    f32x4 acc[2] = {};
    #pragma unroll
    for (int ks = 0; ks < 8; ++ks) {
        int kk = ks * 32 + lk;
        bf16x8 a0 = *(const bf16x8*)&A2[lr][kk];
        #pragma unroll
        for (int ni = 0; ni < 2; ++ni) {
            bf16x8 bF = *(const bf16x8*)(w2b + (size_t)(wn + ni * 16 + lr) * 256 + kk);
            acc[ni] = __builtin_amdgcn_mfma_f32_16x16x32_bf16(a0, bF, acc[ni], 0, 0, 0);
        }
    }
    #pragma unroll
    for (int ni = 0; ni < 2; ++ni) {
        int n = wn + ni * 16 + (lane & 15);
        float bv = b2[n];
        #pragma unroll
        for (int r = 0; r < 4; ++r)
            es[((lane >> 4) << 2) + r][n] = acc[ni][r] + bv;
    }
    __syncthreads();
    if (tid < 128) {   // LN stats: 8 threads/row, 16 rows
        int r = tid >> 3, qq = tid & 7;
        float s = 0.f, s2 = 0.f;
        #pragma unroll
        for (int c = 0; c < 16; ++c) { float v = es[r][qq * 16 + c]; s += v; s2 += v * v; }
        s += __shfl_down(s, 1, 64); s2 += __shfl_down(s2, 1, 64);
        s += __shfl_down(s, 2, 64); s2 += __shfl_down(s2, 2, 64);
        s += __shfl_down(s, 4, 64); s2 += __shfl_down(s2, 4, 64);
        if (qq == 0) {
            float mu = s * (1.f / DD);
            float var = s2 * (1.f / DD) - mu * mu;
            rstat[r][0] = mu; rstat[r][1] = rsqrtf(var + LN_EPS);
        }
    }
    __syncthreads();
    #pragma unroll
    for (int i = 0; i < 2; ++i) {
        int l = tid + i * 256;
        int r = l >> 5, c4 = (l & 31) << 2;
        float mu = rstat[r][0], rs = rstat[r][1];
        size_t off = (size_t)(row0 + r) * DD + c4;
        float4 xo = *(const float4*)(xout + off);
        float4 o;
        o.x = xo.x + (es[r][c4 + 0] - mu) * rs * lg_[c4 + 0] + lb_[c4 + 0];
        o.y = xo.y + (es[r][c4 + 1] - mu) * rs * lg_[c4 + 1] + lb_[c4 + 1];
        o.z = xo.z + (es[r][c4 + 2] - mu) * rs * lg_[c4 + 2] + lb_[c4 + 2];
        o.w = xo.w + (es[r][c4 + 3] - mu) * rs * lg_[c4 + 3] + lb_[c4 + 3];
        *(float4*)(xout + off) = o;
        if (LAST) *(float4*)(out + off) = o;
    }
}

// ---------------------------------------------------------------------------
// A_row (blocks 0..32767) and A_col incl. dump (blocks 32768..65535).
// ---------------------------------------------------------------------------
__global__ __launch_bounds__(256)
void arowcol_kernel(const float* __restrict__ gbuf, const float* __restrict__ denb,
                    float* __restrict__ Arow, float* __restrict__ Acol)
{
    const int tid = threadIdx.x;
    __shared__ int   cols[9];
    __shared__ float vals[9];
    __shared__ float wred[9][4];
    if (blockIdx.x < 32768) {
        const int bi = blockIdx.x;
        const int b = bi >> 12, i = bi & 4095;
        const int h = i >> 10, p = i & 1023;
        const int cy = p >> 5, cx = p & 31;
        if (tid < 9) {
            int dy = tid / 3 - 1, dx = tid % 3 - 1;
            bool valid = ((unsigned)(cy + dy) < (unsigned)HO_) && ((unsigned)(cx + dx) < (unsigned)WO_);
            cols[tid] = valid ? (cy + dy) * WO_ + (cx + dx) : 0;
            vals[tid] = 4.f * gbuf[(((size_t)(b * 4 + h) << 10) + p) * 9 + tid];
        }
        __syncthreads();
        float* row = Arow + (size_t)bi * NOUT;
        #pragma unroll
        for (int cc = 0; cc < 4; ++cc) {
            int c = cc * 256 + tid;
            float acc = 0.f;
            #pragma unroll
            for (int jj = 0; jj < 9; ++jj)
                if (cols[jj] == c) acc += vals[jj];
            row[c] = acc;
        }
    } else {
        const int br = blockIdx.x - 32768;
        const int b = br >> 12, r = br & 4095;
        const int h = r & 3, coarse = r >> 2;
        const int cy = coarse >> 5, cx = coarse & 31;
        if (tid < 9) {
            int dy = tid / 3 - 1, dx = tid % 3 - 1;
            int py = cy - dy, px = cx - dx;
            float v = 0.f;
            if ((unsigned)py < (unsigned)HO_ && (unsigned)px < (unsigned)WO_) {
                int p = py * WO_ + px;
                v = gbuf[(((size_t)(b * 4 + h) << 10) + p) * 9 + tid] / denb[b * NOUT + p];
            }
            vals[tid] = v;
        }
        if (r == 0) {
            float part[9] = {};
            for (int p = tid; p < NOUT; p += 256) {
                float invd = 1.f / denb[b * NOUT + p];
                int py = p >> 5, px = p & 31;
                #pragma unroll
                for (int jj = 0; jj < 9; ++jj) {
                    int dy = jj / 3 - 1, dx = jj % 3 - 1;
                    bool valid = ((unsigned)(py + dy) < (unsigned)HO_) && ((unsigned)(px + dx) < (unsigned)WO_);
                    if (!valid) part[jj] += invd;
                }
            }
            #pragma unroll
            for (int jj = 0; jj < 9; ++jj) {
                float s = part[jj];
                #pragma unroll
                for (int o = 32; o > 0; o >>= 1) s += __shfl_down(s, o, 64);
                if ((tid & 63) == 0) wred[jj][tid >> 6] = s;
            }
            __syncthreads();
            if (tid < 9) {
                float s = wred[tid][0] + wred[tid][1] + wred[tid][2] + wred[tid][3];
                float H = 0.f;
                for (int h2 = 0; h2 < 4; ++h2)
                    H += gbuf[(((size_t)(b * 4 + h2)) << 10) * 9];
                vals[tid] += H * s;
            }
        }
        __syncthreads();
        float* row = Acol + (size_t)br * NOUT;
        #pragma unroll
        for (int cc = 0; cc < 4; ++cc) {
            int c = cc * 256 + tid;
            row[c] = (c < 36) ? vals[c % 9] : 0.f;
        }
    }
}

// ---------------------------------------------------------------------------
extern "C" void kernel_launch(void* const* d_in, const int* in_sizes, int n_in,
                              void* d_out, int out_size, void* d_ws, size_t ws_size,
                              hipStream_t stream)
{
    const float* x        = (const float*)d_in[0];
    const float* seed_w   = (const float*)d_in[1];
    const float* wq       = (const float*)d_in[2];
    const float* wk       = (const float*)d_in[3];
    const float* wv       = (const float*)d_in[4];
    const float* w1       = (const float*)d_in[5];
    const float* b1       = (const float*)d_in[6];
    const float* w2       = (const float*)d_in[7];
    const float* b2       = (const float*)d_in[8];
    const float* ln_in_g  = (const float*)d_in[9];
    const float* ln_in_b  = (const float*)d_in[10];
    const float* ln_out_g = (const float*)d_in[11];
    const float* ln_out_b = (const float*)d_in[12];
    const float* rpb      = (const float*)d_in[13];
    const float* tau      = (const float*)d_in[14];

    float* out  = (float*)d_out;
    float* Arow = out + (size_t)BB * NOUT * DD;
    float* Acol = Arow + (size_t)BB * NIN * NOUT;

    // Must-survive scratch in d_ws:
    float* ws    = (float*)d_ws;
    float* xout  = ws;                                 // 1,048,576
    float* gbuf  = xout + (size_t)BB * NOUT * DD;      // 294,912
    float* denb  = gbuf + (size_t)BB * 4 * NOUT * 9;   // 8,192
    ushort* wb   = (ushort*)(denb + BB * NOUT);        // 262,144 ushorts
    ushort* wkb  = wb;
    ushort* wvb  = wb + 16384;
    ushort* wqb  = wb + 32768;
    ushort* w1b  = wb + 49152;
    ushort* w2b  = wb + 81920;
    ushort* wcb  = wb + 114688;

    // Dead-by-the-end scratch carved from the A_row output region:
    ushort* kbuf = (ushort*)Arow;                       // 4,194,304 ushorts
    ushort* vbuf = kbuf + (size_t)4194304;              // 4,194,304 ushorts
    ushort* h1   = vbuf + (size_t)4194304;              // 2,097,152 ushorts

    // --- preamble ---
    wconvert_kernel<<<1024, 256, 0, stream>>>(wq, wk, wv, w1, w2, seed_w, wb);
    prep_kv_kernel<<<BB * NIN / 64, 256, 0, stream>>>(x, wkb, wvb, ln_in_g, ln_in_b,
                                                      kbuf, vbuf);
    conv_ln_kernel<<<BB * NOUT / 64, 256, 0, stream>>>(x, wcb, ln_out_g, ln_out_b, xout);

    // --- 3 iterations: attnq + ffn1 + ffn2 ---
    for (int it = 0; it < 3; ++it) {
        attnq_kernel<<<BB * HO_, 256, 0, stream>>>(xout, kbuf, vbuf, wqb, ln_out_g,
                                                   ln_out_b, rpb, tau, gbuf, denb);
        ffn1_kernel<<<BB * NOUT / 16, 256, 0, stream>>>(xout, w1b, b1, h1);
        if (it < 2)
            ffn2_kernel<0><<<BB * NOUT / 16, 256, 0, stream>>>(h1, w2b, b2, ln_out_g,
                                                               ln_out_b, xout, out);
        else
            ffn2_kernel<1><<<BB * NOUT / 16, 256, 0, stream>>>(h1, w2b, b2, ln_out_g,
                                                               ln_out_b, xout, out);
    }

    // --- epilogue: A_row + A_col (+dump inline) ---
    arowcol_kernel<<<2 * BB * NIN, 256, 0, stream>>>(gbuf, denb, Arow, Acol);
}

// Round 7
// 203.033 us; speedup vs baseline: 1.3201x; 1.1019x over previous
//
#include <hip/hip_runtime.h>
#include <hip/hip_bf16.h>
#include <math.h>

// Problem constants
#define BB   8
#define HI_  64
#define WI_  64
#define DD   128
#define HO_  32
#define WO_  32
#define NIN  4096
#define NOUT 1024
#define LN_EPS 1e-5f
#define ATT_EPS 1e-6f

typedef short bf16x8 __attribute__((ext_vector_type(8)));
typedef float f32x4  __attribute__((ext_vector_type(4)));

__device__ __forceinline__ ushort f2bf(float f) {
    union { float f; unsigned u; } a; a.f = f;
    unsigned u = a.u;
    return (ushort)((u + 0x7FFFu + ((u >> 16) & 1u)) >> 16);
}
__device__ __forceinline__ float bf2f(ushort u) {
    union { unsigned u; float f; } a; a.u = ((unsigned)u) << 16;
    return a.f;
}

// ---------------------------------------------------------------------------
// Weight conversion to bf16 (+ conv weight transpose to tap-major N x K).
// Layout: [wk 16384][wv 16384][wq 16384][w1 32768][w2 32768][wc 147456]
// ---------------------------------------------------------------------------
__global__ __launch_bounds__(256)
void wconvert_kernel(const float* __restrict__ wq, const float* __restrict__ wk,
                     const float* __restrict__ wv, const float* __restrict__ w1,
                     const float* __restrict__ w2, const float* __restrict__ sw,
                     ushort* __restrict__ dst)
{
    int i = blockIdx.x * 256 + threadIdx.x;   // total 262144
    float v;
    if (i < 16384)        v = wk[i];
    else if (i < 32768)   v = wv[i - 16384];
    else if (i < 49152)   v = wq[i - 32768];
    else if (i < 81920)   v = w1[i - 49152];
    else if (i < 114688)  v = w2[i - 81920];
    else {
        int j = i - 114688;
        int n = j / 1152;
        int rem = j - n * 1152;
        int tap = rem >> 7, di = rem & 127;
        v = sw[((size_t)(n * DD + di)) * 9 + tap];
    }
    dst[i] = f2bf(v);
}

// ---------------------------------------------------------------------------
// prep_kv: per 64-row block of x: LN(x) -> k GEMM, x -> v GEMM, write bf16
// kbuf/vbuf with unfold remap.
// ---------------------------------------------------------------------------
__global__ __launch_bounds__(256)
void prep_kv_kernel(const float* __restrict__ x, const ushort* __restrict__ wkb,
                    const ushort* __restrict__ wvb,
                    const float* __restrict__ lg_, const float* __restrict__ lb_,
                    ushort* __restrict__ kbuf, ushort* __restrict__ vbuf)
{
    __shared__ float  xs[64][132];
    __shared__ ushort Aln[64][136];
    __shared__ ushort Araw[64][136];
    __shared__ ushort Bk[128][136];
    __shared__ ushort Bv[128][136];
    __shared__ float  rstat[64][2];
    const int tid = threadIdx.x;
    const int row0 = blockIdx.x * 64;

    #pragma unroll
    for (int i = 0; i < 8; ++i) {
        int l = tid + i * 256;
        int r = l >> 5, c4 = (l & 31) << 2;
        float4 v = *(const float4*)(x + (size_t)(row0 + r) * DD + c4);
        *(float4*)&xs[r][c4] = v;
        ushort4 o; o.x = f2bf(v.x); o.y = f2bf(v.y); o.z = f2bf(v.z); o.w = f2bf(v.w);
        *(ushort4*)&Araw[r][c4] = o;
    }
    __syncthreads();
    {
        int r = tid >> 2, q = tid & 3;
        float s = 0.f, s2 = 0.f;
        #pragma unroll
        for (int c = 0; c < 32; ++c) { float v = xs[r][q * 32 + c]; s += v; s2 += v * v; }
        s += __shfl_down(s, 1, 64); s2 += __shfl_down(s2, 1, 64);
        s += __shfl_down(s, 2, 64); s2 += __shfl_down(s2, 2, 64);
        if (q == 0) {
            float mu = s * (1.f / DD);
            float var = s2 * (1.f / DD) - mu * mu;
            rstat[r][0] = mu; rstat[r][1] = rsqrtf(var + LN_EPS);
        }
    }
    __syncthreads();
    #pragma unroll
    for (int i = 0; i < 8; ++i) {
        int l = tid + i * 256;
        int r = l >> 5, c4 = (l & 31) << 2;
        float mu = rstat[r][0], rs = rstat[r][1];
        ushort4 o;
        o.x = f2bf((xs[r][c4 + 0] - mu) * rs * lg_[c4 + 0] + lb_[c4 + 0]);
        o.y = f2bf((xs[r][c4 + 1] - mu) * rs * lg_[c4 + 1] + lb_[c4 + 1]);
        o.z = f2bf((xs[r][c4 + 2] - mu) * rs * lg_[c4 + 2] + lb_[c4 + 2]);
        o.w = f2bf((xs[r][c4 + 3] - mu) * rs * lg_[c4 + 3] + lb_[c4 + 3]);
        *(ushort4*)&Aln[r][c4] = o;
    }
    #pragma unroll
    for (int i = 0; i < 8; ++i) {
        int l = tid + i * 256;
        int r = l >> 4, c8 = (l & 15) << 3;
        *(uint4*)&Bk[r][c8] = *(const uint4*)(wkb + (size_t)r * DD + c8);
        *(uint4*)&Bv[r][c8] = *(const uint4*)(wvb + (size_t)r * DD + c8);
    }
    __syncthreads();

    const int wid = tid >> 6, lane = tid & 63;
    const int wm = (wid & 1) * 32, wn = (wid >> 1) * 64;
    const int lr = lane & 15, lk = (lane >> 4) << 3;
    f32x4 ak[2][4] = {}, av[2][4] = {};
    #pragma unroll
    for (int ks = 0; ks < 4; ++ks) {
        int kk = ks * 32 + lk;
        bf16x8 aL[2], aR[2];
        #pragma unroll
        for (int mi = 0; mi < 2; ++mi) {
            aL[mi] = *(const bf16x8*)&Aln[wm + mi * 16 + lr][kk];
            aR[mi] = *(const bf16x8*)&Araw[wm + mi * 16 + lr][kk];
        }
        #pragma unroll
        for (int ni = 0; ni < 4; ++ni) {
            bf16x8 bK = *(const bf16x8*)&Bk[wn + ni * 16 + lr][kk];
            bf16x8 bV = *(const bf16x8*)&Bv[wn + ni * 16 + lr][kk];
            #pragma unroll
            for (int mi = 0; mi < 2; ++mi) {
                ak[mi][ni] = __builtin_amdgcn_mfma_f32_16x16x32_bf16(aL[mi], bK, ak[mi][ni], 0, 0, 0);
                av[mi][ni] = __builtin_amdgcn_mfma_f32_16x16x32_bf16(aR[mi], bV, av[mi][ni], 0, 0, 0);
            }
        }
    }
    #pragma unroll
    for (int mi = 0; mi < 2; ++mi) {
        #pragma unroll
        for (int ni = 0; ni < 4; ++ni) {
            int n = wn + ni * 16 + (lane & 15);
            #pragma unroll
            for (int r = 0; r < 4; ++r) {
                int m = row0 + wm + mi * 16 + ((lane >> 4) << 2) + r;
                int b = m >> 12, pix = m & 4095;
                int iy = pix >> 6, ix = pix & 63;
                int h = ((iy & 1) << 1) | (ix & 1);
                int cp = ((iy >> 1) << 5) | (ix >> 1);
                size_t orow = ((size_t)(b * 4 + h) << 10) + cp;
                kbuf[orow * DD + n] = f2bf(ak[mi][ni][r]);
                vbuf[orow * DD + n] = f2bf(av[mi][ni][r]);
            }
        }
    }
}

// ---------------------------------------------------------------------------
// conv GEMM (im2col gather, K=1152) + LN epilogue -> xout fp32.
// ---------------------------------------------------------------------------
__global__ __launch_bounds__(256)
void conv_ln_kernel(const float* __restrict__ x, const ushort* __restrict__ wcb,
                    const float* __restrict__ lg_, const float* __restrict__ lb_,
                    float* __restrict__ xout)
{
    __shared__ ushort As[64][72];
    __shared__ ushort Bs[128][72];
    __shared__ float  es[64][132];
    __shared__ float  rstat[64][2];
    const int tid = threadIdx.x, wid = tid >> 6, lane = tid & 63;
    const int row0 = blockIdx.x * 64;
    const int wm = (wid & 1) * 32, wn = (wid >> 1) * 64;
    const int lr = lane & 15, lk = (lane >> 4) << 3;
    f32x4 acc[2][4] = {};

    for (int k0 = 0; k0 < 1152; k0 += 64) {
        #pragma unroll
        for (int i = 0; i < 4; ++i) {
            int l = tid + i * 256;
            int r = l >> 4, c4 = (l & 15) << 2;
            int m = row0 + r;
            int b = m >> 10, p = m & 1023;
            int y = p >> 5, xx = p & 31;
            int kg = k0 + c4;
            int tap = kg >> 7, di = kg & 127;
            int ky = tap / 3, kx = tap - ky * 3;
            int iy = 2 * y + ky - 1, ix = 2 * xx + kx - 1;
            float4 v;
            if ((unsigned)iy < (unsigned)HI_ && (unsigned)ix < (unsigned)WI_)
                v = *(const float4*)(x + ((size_t)b * NIN + iy * WI_ + ix) * DD + di);
            else v = make_float4(0.f, 0.f, 0.f, 0.f);
            ushort4 o; o.x = f2bf(v.x); o.y = f2bf(v.y); o.z = f2bf(v.z); o.w = f2bf(v.w);
            *(ushort4*)&As[r][c4] = o;
        }
        #pragma unroll
        for (int i = 0; i < 4; ++i) {
            int l = tid + i * 256;
            int r = l >> 3, c8 = (l & 7) << 3;
            *(uint4*)&Bs[r][c8] = *(const uint4*)(wcb + (size_t)r * 1152 + k0 + c8);
        }
        __syncthreads();
        #pragma unroll
        for (int ks = 0; ks < 2; ++ks) {
            int kk = ks * 32 + lk;
            bf16x8 aF[2];
            aF[0] = *(const bf16x8*)&As[wm + lr][kk];
            aF[1] = *(const bf16x8*)&As[wm + 16 + lr][kk];
            #pragma unroll
            for (int ni = 0; ni < 4; ++ni) {
                bf16x8 bF = *(const bf16x8*)&Bs[wn + ni * 16 + lr][kk];
                acc[0][ni] = __builtin_amdgcn_mfma_f32_16x16x32_bf16(aF[0], bF, acc[0][ni], 0, 0, 0);
                acc[1][ni] = __builtin_amdgcn_mfma_f32_16x16x32_bf16(aF[1], bF, acc[1][ni], 0, 0, 0);
            }
        }
        __syncthreads();
    }
    #pragma unroll
    for (int mi = 0; mi < 2; ++mi)
        #pragma unroll
        for (int ni = 0; ni < 4; ++ni) {
            int n = wn + ni * 16 + (lane & 15);
            #pragma unroll
            for (int r = 0; r < 4; ++r)
                es[wm + mi * 16 + ((lane >> 4) << 2) + r][n] = acc[mi][ni][r];
        }
    __syncthreads();
    {
        int r = tid >> 2, q = tid & 3;
        float s = 0.f, s2 = 0.f;
        #pragma unroll
        for (int c = 0; c < 32; ++c) { float v = es[r][q * 32 + c]; s += v; s2 += v * v; }
        s += __shfl_down(s, 1, 64); s2 += __shfl_down(s2, 1, 64);
        s += __shfl_down(s, 2, 64); s2 += __shfl_down(s2, 2, 64);
        if (q == 0) {
            float mu = s * (1.f / DD);
            float var = s2 * (1.f / DD) - mu * mu;
            rstat[r][0] = mu; rstat[r][1] = rsqrtf(var + LN_EPS);
        }
    }
    __syncthreads();
    #pragma unroll
    for (int i = 0; i < 8; ++i) {
        int l = tid + i * 256;
        int r = l >> 5, c4 = (l & 31) << 2;
        float mu = rstat[r][0], rs = rstat[r][1];
        float4 o;
        o.x = (es[r][c4 + 0] - mu) * rs * lg_[c4 + 0] + lb_[c4 + 0];
        o.y = (es[r][c4 + 1] - mu) * rs * lg_[c4 + 1] + lb_[c4 + 1];
        o.z = (es[r][c4 + 2] - mu) * rs * lg_[c4 + 2] + lb_[c4 + 2];
        o.w = (es[r][c4 + 3] - mu) * rs * lg_[c4 + 3] + lb_[c4 + 3];
        *(float4*)(xout + (size_t)(row0 + r) * DD + c4) = o;
    }
}

// ---------------------------------------------------------------------------
// attnq v2: one block per (b, cy, half) — 16 positions. LN + q-GEMM (direct
// wq fragments) + attention with k/v read DIRECT from global (L2-hot, no LDS
// staging) + AV update. ~25 KB LDS.
// ---------------------------------------------------------------------------
__global__ __launch_bounds__(256)
void attnq_kernel(float* __restrict__ xout, const ushort* __restrict__ kbuf,
                  const ushort* __restrict__ vbuf, const ushort* __restrict__ wqb,
                  const float* __restrict__ lg_, const float* __restrict__ lb_,
                  const float* __restrict__ rpb, const float* __restrict__ tau,
                  float* __restrict__ gbuf, float* __restrict__ denb)
{
    const int bid = blockIdx.x;
    const int b = bid >> 6, cy = (bid >> 1) & 31, cx0 = (bid & 1) << 4;
    const int ry0 = min(max(cy - 1, 0), HO_ - 3);
    const int tid = threadIdx.x;
    const int wid = tid >> 6, lane = tid & 63;
    const int lr = lane & 15, lk = (lane >> 4) << 3;

    __shared__ float  xsf[17][132];
    __shared__ ushort Aq[32][136];
    __shared__ ushort qs[17][136];
    __shared__ float  rstat[17][2];
    __shared__ float  lgp[16][36];
    __shared__ float  lg0[36];
    __shared__ float  sm0[4];
    __shared__ float  den[16];
    __shared__ float  hsum[16][4];

    // ---- P0: load 16-position tile + p0 row; LN -> Aq ----
    for (int l = tid; l < 544; l += 256) {
        int r = l >> 5, c4 = (l & 31) << 2;
        int g = b * NOUT + (r < 16 ? cy * 32 + cx0 + r : 0);
        *(float4*)&xsf[r][c4] = *(const float4*)(xout + (size_t)g * DD + c4);
    }
    __syncthreads();
    if (tid < 68) {
        int r = tid >> 2, q = tid & 3;
        float s = 0.f, s2 = 0.f;
        #pragma unroll
        for (int c = 0; c < 32; ++c) { float v = xsf[r][q * 32 + c]; s += v; s2 += v * v; }
        s += __shfl_down(s, 1, 64); s2 += __shfl_down(s2, 1, 64);
        s += __shfl_down(s, 2, 64); s2 += __shfl_down(s2, 2, 64);
        if (q == 0) {
            float mu = s * (1.f / DD);
            float var = s2 * (1.f / DD) - mu * mu;
            rstat[r][0] = mu; rstat[r][1] = rsqrtf(var + LN_EPS);
        }
    }
    __syncthreads();
    for (int l = tid; l < 544; l += 256) {
        int r = l >> 5, c4 = (l & 31) << 2;
        float mu = rstat[r][0], rs = rstat[r][1];
        ushort4 o;
        o.x = f2bf((xsf[r][c4 + 0] - mu) * rs * lg_[c4 + 0] + lb_[c4 + 0]);
        o.y = f2bf((xsf[r][c4 + 1] - mu) * rs * lg_[c4 + 1] + lb_[c4 + 1]);
        o.z = f2bf((xsf[r][c4 + 2] - mu) * rs * lg_[c4 + 2] + lb_[c4 + 2]);
        o.w = f2bf((xsf[r][c4 + 3] - mu) * rs * lg_[c4 + 3] + lb_[c4 + 3]);
        *(ushort4*)&Aq[r][c4] = o;
    }
    for (int l = tid; l < 480; l += 256) {       // zero rows 17..31
        int r = 17 + (l >> 5), c4 = (l & 31) << 2;
        ushort4 z; z.x = 0; z.y = 0; z.z = 0; z.w = 0;
        *(ushort4*)&Aq[r][c4] = z;
    }
    __syncthreads();

    // ---- P1: q GEMM (M=32, N=128, K=128), wq fragments direct from global ----
    {
        const int wn = wid * 32;
        f32x4 acc[2][2] = {};
        #pragma unroll
        for (int ks = 0; ks < 4; ++ks) {
            int kk = ks * 32 + lk;
            bf16x8 aF[2];
            aF[0] = *(const bf16x8*)&Aq[lr][kk];
            aF[1] = *(const bf16x8*)&Aq[16 + lr][kk];
            #pragma unroll
            for (int ni = 0; ni < 2; ++ni) {
                bf16x8 bF = *(const bf16x8*)(wqb + (size_t)(wn + ni * 16 + lr) * DD + kk);
                acc[0][ni] = __builtin_amdgcn_mfma_f32_16x16x32_bf16(aF[0], bF, acc[0][ni], 0, 0, 0);
                acc[1][ni] = __builtin_amdgcn_mfma_f32_16x16x32_bf16(aF[1], bF, acc[1][ni], 0, 0, 0);
            }
        }
        #pragma unroll
        for (int mi = 0; mi < 2; ++mi)
            #pragma unroll
            for (int ni = 0; ni < 2; ++ni) {
                int n = wn + ni * 16 + (lane & 15);
                #pragma unroll
                for (int r = 0; r < 4; ++r) {
                    int m = mi * 16 + ((lane >> 4) << 2) + r;
                    if (m < 17) qs[m][n] = f2bf(acc[mi][ni][r]);
                }
            }
    }
    __syncthreads();

    // ---- P2: dots — k rows DIRECT from global (L2-hot) ----
    for (int task = tid; task < 612; task += 256) {
        const ushort *kp, *qp;
        int cl = 0, h, jj;
        if (task < 576) {
            cl = task / 36; int t2 = task - cl * 36;
            h = t2 / 9; jj = t2 - h * 9;
            int ky = jj / 3, kx = jj - ky * 3;
            int c = cx0 + cl;
            int nx = min(max(c - 1, 0), WO_ - 3) + kx;
            kp = kbuf + (((size_t)(b * 4 + h) << 10) + (ry0 + ky) * 32 + nx) * DD;
            qp = &qs[cl][0];
        } else {
            int t2 = task - 576;
            h = t2 / 9; jj = t2 - h * 9;
            int ky = jj / 3, kx = jj - ky * 3;
            kp = kbuf + (((size_t)(b * 4 + h) << 10) + ky * 32 + kx) * DD;
            qp = &qs[16][0];
        }
        float s = 0.f;
        #pragma unroll
        for (int d = 0; d < 128; d += 8) {
            uint4 ku = *(const uint4*)(kp + d);
            uint4 qu = *(const uint4*)(qp + d);
            const ushort* kk2 = (const ushort*)&ku;
            const ushort* qq2 = (const ushort*)&qu;
            #pragma unroll
            for (int t = 0; t < 8; ++t) s += bf2f(kk2[t]) * bf2f(qq2[t]);
        }
        if (task < 576) lgp[cl][h * 9 + jj] = s;
        else            lg0[task - 576] = s;
    }
    __syncthreads();

    // ---- softmax (+EPS): 64 (cl,h) groups + 4 p0 groups ----
    if (tid < 68) {
        float scale = expf(tau[0]);
        int h; const float* lptr; int cl = 0;
        if (tid < 64) { cl = tid >> 2; h = tid & 3; lptr = &lgp[cl][h * 9]; }
        else          { h = tid - 64; lptr = &lg0[h * 9]; }
        float tmpv[9], mx = -1e30f;
        #pragma unroll
        for (int jj = 0; jj < 9; ++jj) {
            float v = (lptr[jj] + rpb[h * 9 + jj]) * scale;
            tmpv[jj] = v; mx = fmaxf(mx, v);
        }
        float ss = 0.f;
        #pragma unroll
        for (int jj = 0; jj < 9; ++jj) { tmpv[jj] = expf(tmpv[jj] - mx); ss += tmpv[jj]; }
        float inv = 1.f / ss;
        if (tid < 64) {
            #pragma unroll
            for (int jj = 0; jj < 9; ++jj) lgp[cl][h * 9 + jj] = tmpv[jj] * inv + ATT_EPS;
        } else sm0[h] = tmpv[0] * inv + ATT_EPS;
    }
    __syncthreads();

    // ---- gather -> gbuf, head-sums ----
    if (tid < 64) {
        int cl = tid >> 2, h = tid & 3;
        int c = cx0 + cl;
        float s = 0.f, gv[9];
        #pragma unroll
        for (int jj = 0; jj < 9; ++jj) {
            int dy = jj / 3 - 1, dx = jj % 3 - 1;
            bool valid = ((unsigned)(cy + dy) < (unsigned)HO_) && ((unsigned)(c + dx) < (unsigned)WO_);
            float v = valid ? lgp[cl][h * 9 + jj] : sm0[h];
            gv[jj] = v; s += v;
        }
        float* gp = gbuf + (((size_t)(b * 4 + h) << 10) + cy * 32 + c) * 9;
        #pragma unroll
        for (int jj = 0; jj < 9; ++jj) { gp[jj] = gv[jj]; lgp[cl][h * 9 + jj] = gv[jj]; }
        hsum[cl][h] = s;
    }
    __syncthreads();
    if (tid < 16) {
        float dd = 4.f * (hsum[tid][0] + hsum[tid][1] + hsum[tid][2] + hsum[tid][3]) + ATT_EPS;
        den[tid] = 1.f / dd;
        denb[b * NOUT + cy * 32 + cx0 + tid] = dd;
    }
    __syncthreads();
    if (tid < 64) {
        int cl = tid >> 2, h = tid & 3;
        float inv = den[cl];
        #pragma unroll
        for (int jj = 0; jj < 9; ++jj) lgp[cl][h * 9 + jj] *= inv;
    }
    __syncthreads();

    // ---- AV update: v rows DIRECT from global; 16 threads/position ----
    {
        int cl = tid >> 4, d0 = (tid & 15) << 3;
        int c = cx0 + cl;
        int rx0 = min(max(c - 1, 0), WO_ - 3);
        float acc[8] = {};
        #pragma unroll
        for (int h = 0; h < 4; ++h)
            #pragma unroll
            for (int jj = 0; jj < 9; ++jj) {
                float cf = lgp[cl][h * 9 + jj];
                int ky = jj / 3, kx = jj - ky * 3;
                const ushort* vp = vbuf + (((size_t)(b * 4 + h) << 10) + (ry0 + ky) * 32 + rx0 + kx) * DD + d0;
                uint4 v0 = *(const uint4*)(vp);
                const ushort* vs0 = (const ushort*)&v0;
                #pragma unroll
                for (int t = 0; t < 8; ++t) acc[t] += cf * bf2f(vs0[t]);
            }
        #pragma unroll
        for (int t = 0; t < 8; t += 4) {
            float4 o = *(float4*)&xsf[cl][d0 + t];
            o.x += acc[t]; o.y += acc[t + 1]; o.z += acc[t + 2]; o.w += acc[t + 3];
            *(float4*)&xsf[cl][d0 + t] = o;
        }
    }
    __syncthreads();

    // ---- write updated 16-row tile to xout ----
    for (int l = tid; l < 512; l += 256) {
        int r = l >> 5, c4 = (l & 31) << 2;
        *(float4*)(xout + ((size_t)(b * NOUT + cy * 32 + cx0 + r)) * DD + c4) = *(float4*)&xsf[r][c4];
    }
}

// ---------------------------------------------------------------------------
// Fused FFN: h1 = gelu(xout@w1^T+b1) in LDS; xout += LN(h1@w2^T+b2).
// 16-row tiles (512 blocks); W fragments direct from global (L2-hot).
// LAST also writes final x_out to d_out.
// ---------------------------------------------------------------------------
template<int LAST>
__global__ __launch_bounds__(256)
void ffn_kernel(const ushort* __restrict__ w1b, const ushort* __restrict__ w2b,
                const float* __restrict__ b1, const float* __restrict__ b2,
                const float* __restrict__ lg_, const float* __restrict__ lb_,
                float* __restrict__ xout, float* __restrict__ out)
{
    __shared__ ushort A1[16][136];
    __shared__ ushort h1s[16][264];
    __shared__ float  es[16][132];
    __shared__ float  rstat[16][2];
    const int tid = threadIdx.x, wid = tid >> 6, lane = tid & 63;
    const int row0 = blockIdx.x * 16;
    const int lr = lane & 15, lk = (lane >> 4) << 3;

    #pragma unroll
    for (int i = 0; i < 2; ++i) {               // A: 512 float4 -> bf16
        int l = tid + i * 256;
        int r = l >> 5, c4 = (l & 31) << 2;
        float4 v = *(const float4*)(xout + (size_t)(row0 + r) * DD + c4);
        ushort4 o; o.x = f2bf(v.x); o.y = f2bf(v.y); o.z = f2bf(v.z); o.w = f2bf(v.w);
        *(ushort4*)&A1[r][c4] = o;
    }
    __syncthreads();
    {   // FFN1: N=256 (4 waves x 64), K=128, gelu -> h1s
        const int wn = wid * 64;
        f32x4 acc[4] = {};
        #pragma unroll
        for (int ks = 0; ks < 4; ++ks) {
            int kk = ks * 32 + lk;
            bf16x8 a0 = *(const bf16x8*)&A1[lr][kk];
            #pragma unroll
            for (int ni = 0; ni < 4; ++ni) {
                bf16x8 bF = *(const bf16x8*)(w1b + (size_t)(wn + ni * 16 + lr) * DD + kk);
                acc[ni] = __builtin_amdgcn_mfma_f32_16x16x32_bf16(a0, bF, acc[ni], 0, 0, 0);
            }
        }
        #pragma unroll
        for (int ni = 0; ni < 4; ++ni) {
            int n = wn + ni * 16 + (lane & 15);
            float bv = b1[n];
            #pragma unroll
            for (int r = 0; r < 4; ++r) {
                int m = ((lane >> 4) << 2) + r;
                float v = acc[ni][r] + bv;
                v = 0.5f * v * (1.f + erff(v * 0.70710678118654752f));
                h1s[m][n] = f2bf(v);
            }
        }
    }
    __syncthreads();
    {   // FFN2: N=128 (4 waves x 32), K=256
        const int wn = wid * 32;
        f32x4 acc[2] = {};
        #pragma unroll
        for (int ks = 0; ks < 8; ++ks) {
            int kk = ks * 32 + lk;
            bf16x8 a0 = *(const bf16x8*)&h1s[lr][kk];
            #pragma unroll
            for (int ni = 0; ni < 2; ++ni) {
                bf16x8 bF = *(const bf16x8*)(w2b + (size_t)(wn + ni * 16 + lr) * 256 + kk);
                acc[ni] = __builtin_amdgcn_mfma_f32_16x16x32_bf16(a0, bF, acc[ni], 0, 0, 0);
            }
        }
        #pragma unroll
        for (int ni = 0; ni < 2; ++ni) {
            int n = wn + ni * 16 + (lane & 15);
            float bv = b2[n];
            #pragma unroll
            for (int r = 0; r < 4; ++r)
                es[((lane >> 4) << 2) + r][n] = acc[ni][r] + bv;
        }
    }
    __syncthreads();
    if (tid < 128) {   // LN stats: 8 threads/row, 16 rows
        int r = tid >> 3, qq = tid & 7;
        float s = 0.f, s2 = 0.f;
        #pragma unroll
        for (int c = 0; c < 16; ++c) { float v = es[r][qq * 16 + c]; s += v; s2 += v * v; }
        s += __shfl_down(s, 1, 64); s2 += __shfl_down(s2, 1, 64);
        s += __shfl_down(s, 2, 64); s2 += __shfl_down(s2, 2, 64);
        s += __shfl_down(s, 4, 64); s2 += __shfl_down(s2, 4, 64);
        if (qq == 0) {
            float mu = s * (1.f / DD);
            float var = s2 * (1.f / DD) - mu * mu;
            rstat[r][0] = mu; rstat[r][1] = rsqrtf(var + LN_EPS);
        }
    }
    __syncthreads();
    #pragma unroll
    for (int i = 0; i < 2; ++i) {
        int l = tid + i * 256;
        int r = l >> 5, c4 = (l & 31) << 2;
        float mu = rstat[r][0], rs = rstat[r][1];
        size_t off = (size_t)(row0 + r) * DD + c4;
        float4 xo = *(const float4*)(xout + off);
        float4 o;
        o.x = xo.x + (es[r][c4 + 0] - mu) * rs * lg_[c4 + 0] + lb_[c4 + 0];
        o.y = xo.y + (es[r][c4 + 1] - mu) * rs * lg_[c4 + 1] + lb_[c4 + 1];
        o.z = xo.z + (es[r][c4 + 2] - mu) * rs * lg_[c4 + 2] + lb_[c4 + 2];
        o.w = xo.w + (es[r][c4 + 3] - mu) * rs * lg_[c4 + 3] + lb_[c4 + 3];
        *(float4*)(xout + off) = o;
        if (LAST) *(float4*)(out + off) = o;
    }
}

// ---------------------------------------------------------------------------
// A_row (blocks 0..32767) and A_col incl. dump (blocks 32768..65535).
// ---------------------------------------------------------------------------
__global__ __launch_bounds__(256)
void arowcol_kernel(const float* __restrict__ gbuf, const float* __restrict__ denb,
                    float* __restrict__ Arow, float* __restrict__ Acol)
{
    const int tid = threadIdx.x;
    __shared__ int   cols[9];
    __shared__ float vals[9];
    __shared__ float wred[9][4];
    if (blockIdx.x < 32768) {
        const int bi = blockIdx.x;
        const int b = bi >> 12, i = bi & 4095;
        const int h = i >> 10, p = i & 1023;
        const int cy = p >> 5, cx = p & 31;
        if (tid < 9) {
            int dy = tid / 3 - 1, dx = tid % 3 - 1;
            bool valid = ((unsigned)(cy + dy) < (unsigned)HO_) && ((unsigned)(cx + dx) < (unsigned)WO_);
            cols[tid] = valid ? (cy + dy) * WO_ + (cx + dx) : 0;
            vals[tid] = 4.f * gbuf[(((size_t)(b * 4 + h) << 10) + p) * 9 + tid];
        }
        __syncthreads();
        float* row = Arow + (size_t)bi * NOUT;
        #pragma unroll
        for (int cc = 0; cc < 4; ++cc) {
            int c = cc * 256 + tid;
            float acc = 0.f;
            #pragma unroll
            for (int jj = 0; jj < 9; ++jj)
                if (cols[jj] == c) acc += vals[jj];
            row[c] = acc;
        }
    } else {
        const int br = blockIdx.x - 32768;
        const int b = br >> 12, r = br & 4095;
        const int h = r & 3, coarse = r >> 2;
        const int cy = coarse >> 5, cx = coarse & 31;
        if (tid < 9) {
            int dy = tid / 3 - 1, dx = tid % 3 - 1;
            int py = cy - dy, px = cx - dx;
            float v = 0.f;
            if ((unsigned)py < (unsigned)HO_ && (unsigned)px < (unsigned)WO_) {
                int p = py * WO_ + px;
                v = gbuf[(((size_t)(b * 4 + h) << 10) + p) * 9 + tid] / denb[b * NOUT + p];
            }
            vals[tid] = v;
        }
        if (r == 0) {
            float part[9] = {};
            for (int p = tid; p < NOUT; p += 256) {
                float invd = 1.f / denb[b * NOUT + p];
                int py = p >> 5, px = p & 31;
                #pragma unroll
                for (int jj = 0; jj < 9; ++jj) {
                    int dy = jj / 3 - 1, dx = jj % 3 - 1;
                    bool valid = ((unsigned)(py + dy) < (unsigned)HO_) && ((unsigned)(px + dx) < (unsigned)WO_);
                    if (!valid) part[jj] += invd;
                }
            }
            #pragma unroll
            for (int jj = 0; jj < 9; ++jj) {
                float s = part[jj];
                #pragma unroll
                for (int o = 32; o > 0; o >>= 1) s += __shfl_down(s, o, 64);
                if ((tid & 63) == 0) wred[jj][tid >> 6] = s;
            }
            __syncthreads();
            if (tid < 9) {
                float s = wred[tid][0] + wred[tid][1] + wred[tid][2] + wred[tid][3];
                float H = 0.f;
                for (int h2 = 0; h2 < 4; ++h2)
                    H += gbuf[(((size_t)(b * 4 + h2)) << 10) * 9];
                vals[tid] += H * s;
            }
        }
        __syncthreads();
        float* row = Acol + (size_t)br * NOUT;
        #pragma unroll
        for (int cc = 0; cc < 4; ++cc) {
            int c = cc * 256 + tid;
            row[c] = (c < 36) ? vals[c % 9] : 0.f;
        }
    }
}

// ---------------------------------------------------------------------------
extern "C" void kernel_launch(void* const* d_in, const int* in_sizes, int n_in,
                              void* d_out, int out_size, void* d_ws, size_t ws_size,
                              hipStream_t stream)
{
    const float* x        = (const float*)d_in[0];
    const float* seed_w   = (const float*)d_in[1];
    const float* wq       = (const float*)d_in[2];
    const float* wk       = (const float*)d_in[3];
    const float* wv       = (const float*)d_in[4];
    const float* w1       = (const float*)d_in[5];
    const float* b1       = (const float*)d_in[6];
    const float* w2       = (const float*)d_in[7];
    const float* b2       = (const float*)d_in[8];
    const float* ln_in_g  = (const float*)d_in[9];
    const float* ln_in_b  = (const float*)d_in[10];
    const float* ln_out_g = (const float*)d_in[11];
    const float* ln_out_b = (const float*)d_in[12];
    const float* rpb      = (const float*)d_in[13];
    const float* tau      = (const float*)d_in[14];

    float* out  = (float*)d_out;
    float* Arow = out + (size_t)BB * NOUT * DD;
    float* Acol = Arow + (size_t)BB * NIN * NOUT;

    // Must-survive scratch in d_ws:
    float* ws    = (float*)d_ws;
    float* xout  = ws;                                 // 1,048,576
    float* gbuf  = xout + (size_t)BB * NOUT * DD;      // 294,912
    float* denb  = gbuf + (size_t)BB * 4 * NOUT * 9;   // 8,192
    ushort* wb   = (ushort*)(denb + BB * NOUT);        // 262,144 ushorts
    ushort* wkb  = wb;
    ushort* wvb  = wb + 16384;
    ushort* wqb  = wb + 32768;
    ushort* w1b  = wb + 49152;
    ushort* w2b  = wb + 81920;
    ushort* wcb  = wb + 114688;

    // Dead-by-the-end scratch carved from the A_row output region:
    ushort* kbuf = (ushort*)Arow;                       // 4,194,304 ushorts
    ushort* vbuf = kbuf + (size_t)4194304;              // 4,194,304 ushorts

    // --- preamble ---
    wconvert_kernel<<<1024, 256, 0, stream>>>(wq, wk, wv, w1, w2, seed_w, wb);
    prep_kv_kernel<<<BB * NIN / 64, 256, 0, stream>>>(x, wkb, wvb, ln_in_g, ln_in_b,
                                                      kbuf, vbuf);
    conv_ln_kernel<<<BB * NOUT / 64, 256, 0, stream>>>(x, wcb, ln_out_g, ln_out_b, xout);

    // --- 3 iterations: attnq (512 blocks) + fused ffn (512 blocks) ---
    for (int it = 0; it < 3; ++it) {
        attnq_kernel<<<BB * HO_ * 2, 256, 0, stream>>>(xout, kbuf, vbuf, wqb, ln_out_g,
                                                       ln_out_b, rpb, tau, gbuf, denb);
        if (it < 2)
            ffn_kernel<0><<<BB * NOUT / 16, 256, 0, stream>>>(w1b, w2b, b1, b2, ln_out_g,
                                                              ln_out_b, xout, out);
        else
            ffn_kernel<1><<<BB * NOUT / 16, 256, 0, stream>>>(w1b, w2b, b1, b2, ln_out_g,
                                                              ln_out_b, xout, out);
    }

    // --- epilogue: A_row + A_col (+dump inline) ---
    arowcol_kernel<<<2 * BB * NIN, 256, 0, stream>>>(gbuf, denb, Arow, Acol);
}

// Round 8
// 190.075 us; speedup vs baseline: 1.4101x; 1.0682x over previous
//
#include <hip/hip_runtime.h>
#include <hip/hip_bf16.h>
#include <math.h>

// Problem constants
#define BB   8
#define HI_  64
#define WI_  64
#define DD   128
#define HO_  32
#define WO_  32
#define NIN  4096
#define NOUT 1024
#define LN_EPS 1e-5f
#define ATT_EPS 1e-6f

typedef short bf16x8 __attribute__((ext_vector_type(8)));
typedef float f32x4  __attribute__((ext_vector_type(4)));

__device__ __forceinline__ ushort f2bf(float f) {
    union { float f; unsigned u; } a; a.f = f;
    unsigned u = a.u;
    return (ushort)((u + 0x7FFFu + ((u >> 16) & 1u)) >> 16);
}
__device__ __forceinline__ float bf2f(ushort u) {
    union { unsigned u; float f; } a; a.u = ((unsigned)u) << 16;
    return a.f;
}

// ---------------------------------------------------------------------------
// Weight conversion to bf16 (+ conv weight transpose to tap-major N x K).
// Layout: [wk 16384][wv 16384][wq 16384][w1 32768][w2 32768][wc 147456]
// ---------------------------------------------------------------------------
__global__ __launch_bounds__(256)
void wconvert_kernel(const float* __restrict__ wq, const float* __restrict__ wk,
                     const float* __restrict__ wv, const float* __restrict__ w1,
                     const float* __restrict__ w2, const float* __restrict__ sw,
                     ushort* __restrict__ dst)
{
    int i = blockIdx.x * 256 + threadIdx.x;   // total 262144
    float v;
    if (i < 16384)        v = wk[i];
    else if (i < 32768)   v = wv[i - 16384];
    else if (i < 49152)   v = wq[i - 32768];
    else if (i < 81920)   v = w1[i - 49152];
    else if (i < 114688)  v = w2[i - 81920];
    else {
        int j = i - 114688;
        int n = j / 1152;
        int rem = j - n * 1152;
        int tap = rem >> 7, di = rem & 127;
        v = sw[((size_t)(n * DD + di)) * 9 + tap];
    }
    dst[i] = f2bf(v);
}

// ---------------------------------------------------------------------------
// Merged preamble: blocks 0..511 = prep_kv (64-row tiles of x -> k,v bf16,
// unfold remap); blocks 512..639 = conv GEMM (im2col, K=1152) + LN -> xout.
// Shared-LDS arena sized for the larger branch (138,752 B -> 1 block/CU).
// ---------------------------------------------------------------------------
__global__ __launch_bounds__(256)
void prep_kernel(const float* __restrict__ x, const ushort* __restrict__ wkb,
                 const ushort* __restrict__ wvb, const ushort* __restrict__ wcb,
                 const float* __restrict__ ligg, const float* __restrict__ libb,
                 const float* __restrict__ logg, const float* __restrict__ lobb,
                 ushort* __restrict__ kbuf, ushort* __restrict__ vbuf,
                 float* __restrict__ xout)
{
    __shared__ __align__(16) char arena[138752];
    const int tid = threadIdx.x;
    const int wid = tid >> 6, lane = tid & 63;
    const int lr = lane & 15, lk = (lane >> 4) << 3;

    if (blockIdx.x < 512) {
        // ================= prep_kv =================
        float  (*xs)[132]   = (float  (*)[132])(arena);            // 33792
        ushort (*Aln)[136]  = (ushort (*)[136])(arena + 33792);    // 17408
        ushort (*Araw)[136] = (ushort (*)[136])(arena + 51200);    // 17408
        ushort (*Bk)[136]   = (ushort (*)[136])(arena + 68608);    // 34816
        ushort (*Bv)[136]   = (ushort (*)[136])(arena + 103424);   // 34816
        float  (*rstat)[2]  = (float  (*)[2])(arena + 138240);     // 512
        const int row0 = blockIdx.x * 64;

        #pragma unroll
        for (int i = 0; i < 8; ++i) {
            int l = tid + i * 256;
            int r = l >> 5, c4 = (l & 31) << 2;
            float4 v = *(const float4*)(x + (size_t)(row0 + r) * DD + c4);
            *(float4*)&xs[r][c4] = v;
            ushort4 o; o.x = f2bf(v.x); o.y = f2bf(v.y); o.z = f2bf(v.z); o.w = f2bf(v.w);
            *(ushort4*)&Araw[r][c4] = o;
        }
        __syncthreads();
        {
            int r = tid >> 2, q = tid & 3;
            float s = 0.f, s2 = 0.f;
            #pragma unroll
            for (int c = 0; c < 32; ++c) { float v = xs[r][q * 32 + c]; s += v; s2 += v * v; }
            s += __shfl_down(s, 1, 64); s2 += __shfl_down(s2, 1, 64);
            s += __shfl_down(s, 2, 64); s2 += __shfl_down(s2, 2, 64);
            if (q == 0) {
                float mu = s * (1.f / DD);
                float var = s2 * (1.f / DD) - mu * mu;
                rstat[r][0] = mu; rstat[r][1] = rsqrtf(var + LN_EPS);
            }
        }
        __syncthreads();
        #pragma unroll
        for (int i = 0; i < 8; ++i) {
            int l = tid + i * 256;
            int r = l >> 5, c4 = (l & 31) << 2;
            float mu = rstat[r][0], rs = rstat[r][1];
            ushort4 o;
            o.x = f2bf((xs[r][c4 + 0] - mu) * rs * ligg[c4 + 0] + libb[c4 + 0]);
            o.y = f2bf((xs[r][c4 + 1] - mu) * rs * ligg[c4 + 1] + libb[c4 + 1]);
            o.z = f2bf((xs[r][c4 + 2] - mu) * rs * ligg[c4 + 2] + libb[c4 + 2]);
            o.w = f2bf((xs[r][c4 + 3] - mu) * rs * ligg[c4 + 3] + libb[c4 + 3]);
            *(ushort4*)&Aln[r][c4] = o;
        }
        #pragma unroll
        for (int i = 0; i < 8; ++i) {
            int l = tid + i * 256;
            int r = l >> 4, c8 = (l & 15) << 3;
            *(uint4*)&Bk[r][c8] = *(const uint4*)(wkb + (size_t)r * DD + c8);
            *(uint4*)&Bv[r][c8] = *(const uint4*)(wvb + (size_t)r * DD + c8);
        }
        __syncthreads();

        const int wm = (wid & 1) * 32, wn = (wid >> 1) * 64;
        f32x4 ak[2][4] = {}, av[2][4] = {};
        #pragma unroll
        for (int ks = 0; ks < 4; ++ks) {
            int kk = ks * 32 + lk;
            bf16x8 aL[2], aR[2];
            #pragma unroll
            for (int mi = 0; mi < 2; ++mi) {
                aL[mi] = *(const bf16x8*)&Aln[wm + mi * 16 + lr][kk];
                aR[mi] = *(const bf16x8*)&Araw[wm + mi * 16 + lr][kk];
            }
            #pragma unroll
            for (int ni = 0; ni < 4; ++ni) {
                bf16x8 bK = *(const bf16x8*)&Bk[wn + ni * 16 + lr][kk];
                bf16x8 bV = *(const bf16x8*)&Bv[wn + ni * 16 + lr][kk];
                #pragma unroll
                for (int mi = 0; mi < 2; ++mi) {
                    ak[mi][ni] = __builtin_amdgcn_mfma_f32_16x16x32_bf16(aL[mi], bK, ak[mi][ni], 0, 0, 0);
                    av[mi][ni] = __builtin_amdgcn_mfma_f32_16x16x32_bf16(aR[mi], bV, av[mi][ni], 0, 0, 0);
                }
            }
        }
        #pragma unroll
        for (int mi = 0; mi < 2; ++mi) {
            #pragma unroll
            for (int ni = 0; ni < 4; ++ni) {
                int n = wn + ni * 16 + (lane & 15);
                #pragma unroll
                for (int r = 0; r < 4; ++r) {
                    int m = row0 + wm + mi * 16 + ((lane >> 4) << 2) + r;
                    int b = m >> 12, pix = m & 4095;
                    int iy = pix >> 6, ix = pix & 63;
                    int h = ((iy & 1) << 1) | (ix & 1);
                    int cp = ((iy >> 1) << 5) | (ix >> 1);
                    size_t orow = ((size_t)(b * 4 + h) << 10) + cp;
                    kbuf[orow * DD + n] = f2bf(ak[mi][ni][r]);
                    vbuf[orow * DD + n] = f2bf(av[mi][ni][r]);
                }
            }
        }
    } else {
        // ================= conv + LN =================
        ushort (*As)[72]   = (ushort (*)[72])(arena);              // 9216
        ushort (*Bs)[72]   = (ushort (*)[72])(arena + 9216);       // 18432
        float  (*es)[132]  = (float  (*)[132])(arena + 27648);     // 33792
        float  (*rstat)[2] = (float  (*)[2])(arena + 61440);       // 512
        const int row0 = (blockIdx.x - 512) * 64;
        const int wm = (wid & 1) * 32, wn = (wid >> 1) * 64;
        f32x4 acc[2][4] = {};

        for (int k0 = 0; k0 < 1152; k0 += 64) {
            #pragma unroll
            for (int i = 0; i < 4; ++i) {
                int l = tid + i * 256;
                int r = l >> 4, c4 = (l & 15) << 2;
                int m = row0 + r;
                int b = m >> 10, p = m & 1023;
                int y = p >> 5, xx = p & 31;
                int kg = k0 + c4;
                int tap = kg >> 7, di = kg & 127;
                int ky = tap / 3, kx = tap - ky * 3;
                int iy = 2 * y + ky - 1, ix = 2 * xx + kx - 1;
                float4 v;
                if ((unsigned)iy < (unsigned)HI_ && (unsigned)ix < (unsigned)WI_)
                    v = *(const float4*)(x + ((size_t)b * NIN + iy * WI_ + ix) * DD + di);
                else v = make_float4(0.f, 0.f, 0.f, 0.f);
                ushort4 o; o.x = f2bf(v.x); o.y = f2bf(v.y); o.z = f2bf(v.z); o.w = f2bf(v.w);
                *(ushort4*)&As[r][c4] = o;
            }
            #pragma unroll
            for (int i = 0; i < 4; ++i) {
                int l = tid + i * 256;
                int r = l >> 3, c8 = (l & 7) << 3;
                *(uint4*)&Bs[r][c8] = *(const uint4*)(wcb + (size_t)r * 1152 + k0 + c8);
            }
            __syncthreads();
            #pragma unroll
            for (int ks = 0; ks < 2; ++ks) {
                int kk = ks * 32 + lk;
                bf16x8 aF[2];
                aF[0] = *(const bf16x8*)&As[wm + lr][kk];
                aF[1] = *(const bf16x8*)&As[wm + 16 + lr][kk];
                #pragma unroll
                for (int ni = 0; ni < 4; ++ni) {
                    bf16x8 bF = *(const bf16x8*)&Bs[wn + ni * 16 + lr][kk];
                    acc[0][ni] = __builtin_amdgcn_mfma_f32_16x16x32_bf16(aF[0], bF, acc[0][ni], 0, 0, 0);
                    acc[1][ni] = __builtin_amdgcn_mfma_f32_16x16x32_bf16(aF[1], bF, acc[1][ni], 0, 0, 0);
                }
            }
            __syncthreads();
        }
        #pragma unroll
        for (int mi = 0; mi < 2; ++mi)
            #pragma unroll
            for (int ni = 0; ni < 4; ++ni) {
                int n = wn + ni * 16 + (lane & 15);
                #pragma unroll
                for (int r = 0; r < 4; ++r)
                    es[wm + mi * 16 + ((lane >> 4) << 2) + r][n] = acc[mi][ni][r];
            }
        __syncthreads();
        {
            int r = tid >> 2, q = tid & 3;
            float s = 0.f, s2 = 0.f;
            #pragma unroll
            for (int c = 0; c < 32; ++c) { float v = es[r][q * 32 + c]; s += v; s2 += v * v; }
            s += __shfl_down(s, 1, 64); s2 += __shfl_down(s2, 1, 64);
            s += __shfl_down(s, 2, 64); s2 += __shfl_down(s2, 2, 64);
            if (q == 0) {
                float mu = s * (1.f / DD);
                float var = s2 * (1.f / DD) - mu * mu;
                rstat[r][0] = mu; rstat[r][1] = rsqrtf(var + LN_EPS);
            }
        }
        __syncthreads();
        #pragma unroll
        for (int i = 0; i < 8; ++i) {
            int l = tid + i * 256;
            int r = l >> 5, c4 = (l & 31) << 2;
            float mu = rstat[r][0], rs = rstat[r][1];
            float4 o;
            o.x = (es[r][c4 + 0] - mu) * rs * logg[c4 + 0] + lobb[c4 + 0];
            o.y = (es[r][c4 + 1] - mu) * rs * logg[c4 + 1] + lobb[c4 + 1];
            o.z = (es[r][c4 + 2] - mu) * rs * logg[c4 + 2] + lobb[c4 + 2];
            o.w = (es[r][c4 + 3] - mu) * rs * logg[c4 + 3] + lobb[c4 + 3];
            *(float4*)(xout + (size_t)(row0 + r) * DD + c4) = o;
        }
    }
}

// ---------------------------------------------------------------------------
// Fused iteration: one block per (b, cy, half) = 16 positions.
// LN + q-GEMM (direct wq frags) + attention (k/v direct from global, L2-hot)
// + AV update + FFN1(gelu) + FFN2 + LN + residual — all on the LDS tile.
// Writes gbuf, denb, xout (+d_out on LAST). ~42 KB LDS -> 2 blocks/CU.
// ---------------------------------------------------------------------------
template<int LAST>
__global__ __launch_bounds__(256)
void iter_kernel(float* __restrict__ xout, const ushort* __restrict__ kbuf,
                 const ushort* __restrict__ vbuf, const ushort* __restrict__ wqb,
                 const ushort* __restrict__ w1b, const ushort* __restrict__ w2b,
                 const float* __restrict__ b1, const float* __restrict__ b2,
                 const float* __restrict__ lg_, const float* __restrict__ lb_,
                 const float* __restrict__ rpb, const float* __restrict__ tau,
                 float* __restrict__ gbuf, float* __restrict__ denb,
                 float* __restrict__ out)
{
    const int bid = blockIdx.x;
    const int b = bid >> 6, cy = (bid >> 1) & 31, cx0 = (bid & 1) << 4;
    const int ry0 = min(max(cy - 1, 0), HO_ - 3);
    const int tid = threadIdx.x;
    const int wid = tid >> 6, lane = tid & 63;
    const int lr = lane & 15, lk = (lane >> 4) << 3;

    __shared__ float  xsf[17][132];
    __shared__ ushort Aq[32][136];       // LN(x) for q GEMM; reused as FFN1 A
    __shared__ ushort qs[17][136];
    __shared__ float  rstat[17][2];
    __shared__ float  lgp[16][36];
    __shared__ float  lg0[36];
    __shared__ float  sm0[4];
    __shared__ float  den[16];
    __shared__ float  hsum[16][4];
    __shared__ ushort h1s[16][264];
    __shared__ float  es[16][132];

    // ---- P0: load 16-position tile + p0 row; LN -> Aq ----
    for (int l = tid; l < 544; l += 256) {
        int r = l >> 5, c4 = (l & 31) << 2;
        int g = b * NOUT + (r < 16 ? cy * 32 + cx0 + r : 0);
        *(float4*)&xsf[r][c4] = *(const float4*)(xout + (size_t)g * DD + c4);
    }
    __syncthreads();
    if (tid < 68) {
        int r = tid >> 2, q = tid & 3;
        float s = 0.f, s2 = 0.f;
        #pragma unroll
        for (int c = 0; c < 32; ++c) { float v = xsf[r][q * 32 + c]; s += v; s2 += v * v; }
        s += __shfl_down(s, 1, 64); s2 += __shfl_down(s2, 1, 64);
        s += __shfl_down(s, 2, 64); s2 += __shfl_down(s2, 2, 64);
        if (q == 0) {
            float mu = s * (1.f / DD);
            float var = s2 * (1.f / DD) - mu * mu;
            rstat[r][0] = mu; rstat[r][1] = rsqrtf(var + LN_EPS);
        }
    }
    __syncthreads();
    for (int l = tid; l < 544; l += 256) {
        int r = l >> 5, c4 = (l & 31) << 2;
        float mu = rstat[r][0], rs = rstat[r][1];
        ushort4 o;
        o.x = f2bf((xsf[r][c4 + 0] - mu) * rs * lg_[c4 + 0] + lb_[c4 + 0]);
        o.y = f2bf((xsf[r][c4 + 1] - mu) * rs * lg_[c4 + 1] + lb_[c4 + 1]);
        o.z = f2bf((xsf[r][c4 + 2] - mu) * rs * lg_[c4 + 2] + lb_[c4 + 2]);
        o.w = f2bf((xsf[r][c4 + 3] - mu) * rs * lg_[c4 + 3] + lb_[c4 + 3]);
        *(ushort4*)&Aq[r][c4] = o;
    }
    for (int l = tid; l < 480; l += 256) {       // zero rows 17..31
        int r = 17 + (l >> 5), c4 = (l & 31) << 2;
        ushort4 z; z.x = 0; z.y = 0; z.z = 0; z.w = 0;
        *(ushort4*)&Aq[r][c4] = z;
    }
    __syncthreads();

    // ---- P1: q GEMM (M=32, N=128, K=128), wq fragments direct from global ----
    {
        const int wn = wid * 32;
        f32x4 acc[2][2] = {};
        #pragma unroll
        for (int ks = 0; ks < 4; ++ks) {
            int kk = ks * 32 + lk;
            bf16x8 aF[2];
            aF[0] = *(const bf16x8*)&Aq[lr][kk];
            aF[1] = *(const bf16x8*)&Aq[16 + lr][kk];
            #pragma unroll
            for (int ni = 0; ni < 2; ++ni) {
                bf16x8 bF = *(const bf16x8*)(wqb + (size_t)(wn + ni * 16 + lr) * DD + kk);
                acc[0][ni] = __builtin_amdgcn_mfma_f32_16x16x32_bf16(aF[0], bF, acc[0][ni], 0, 0, 0);
                acc[1][ni] = __builtin_amdgcn_mfma_f32_16x16x32_bf16(aF[1], bF, acc[1][ni], 0, 0, 0);
            }
        }
        #pragma unroll
        for (int mi = 0; mi < 2; ++mi)
            #pragma unroll
            for (int ni = 0; ni < 2; ++ni) {
                int n = wn + ni * 16 + (lane & 15);
                #pragma unroll
                for (int r = 0; r < 4; ++r) {
                    int m = mi * 16 + ((lane >> 4) << 2) + r;
                    if (m < 17) qs[m][n] = f2bf(acc[mi][ni][r]);
                }
            }
    }
    __syncthreads();

    // ---- P2: dots — k rows DIRECT from global (L2-hot) ----
    for (int task = tid; task < 612; task += 256) {
        const ushort *kp, *qp;
        int cl = 0, h, jj;
        if (task < 576) {
            cl = task / 36; int t2 = task - cl * 36;
            h = t2 / 9; jj = t2 - h * 9;
            int ky = jj / 3, kx = jj - ky * 3;
            int c = cx0 + cl;
            int nx = min(max(c - 1, 0), WO_ - 3) + kx;
            kp = kbuf + (((size_t)(b * 4 + h) << 10) + (ry0 + ky) * 32 + nx) * DD;
            qp = &qs[cl][0];
        } else {
            int t2 = task - 576;
            h = t2 / 9; jj = t2 - h * 9;
            int ky = jj / 3, kx = jj - ky * 3;
            kp = kbuf + (((size_t)(b * 4 + h) << 10) + ky * 32 + kx) * DD;
            qp = &qs[16][0];
        }
        float s = 0.f;
        #pragma unroll
        for (int d = 0; d < 128; d += 8) {
            uint4 ku = *(const uint4*)(kp + d);
            uint4 qu = *(const uint4*)(qp + d);
            const ushort* kk2 = (const ushort*)&ku;
            const ushort* qq2 = (const ushort*)&qu;
            #pragma unroll
            for (int t = 0; t < 8; ++t) s += bf2f(kk2[t]) * bf2f(qq2[t]);
        }
        if (task < 576) lgp[cl][h * 9 + jj] = s;
        else            lg0[task - 576] = s;
    }
    __syncthreads();

    // ---- softmax (+EPS): 64 (cl,h) groups + 4 p0 groups ----
    if (tid < 68) {
        float scale = expf(tau[0]);
        int h; const float* lptr; int cl = 0;
        if (tid < 64) { cl = tid >> 2; h = tid & 3; lptr = &lgp[cl][h * 9]; }
        else          { h = tid - 64; lptr = &lg0[h * 9]; }
        float tmpv[9], mx = -1e30f;
        #pragma unroll
        for (int jj = 0; jj < 9; ++jj) {
            float v = (lptr[jj] + rpb[h * 9 + jj]) * scale;
            tmpv[jj] = v; mx = fmaxf(mx, v);
        }
        float ss = 0.f;
        #pragma unroll
        for (int jj = 0; jj < 9; ++jj) { tmpv[jj] = expf(tmpv[jj] - mx); ss += tmpv[jj]; }
        float inv = 1.f / ss;
        if (tid < 64) {
            #pragma unroll
            for (int jj = 0; jj < 9; ++jj) lgp[cl][h * 9 + jj] = tmpv[jj] * inv + ATT_EPS;
        } else sm0[h] = tmpv[0] * inv + ATT_EPS;
    }
    __syncthreads();

    // ---- gather -> gbuf, head-sums ----
    if (tid < 64) {
        int cl = tid >> 2, h = tid & 3;
        int c = cx0 + cl;
        float s = 0.f, gv[9];
        #pragma unroll
        for (int jj = 0; jj < 9; ++jj) {
            int dy = jj / 3 - 1, dx = jj % 3 - 1;
            bool valid = ((unsigned)(cy + dy) < (unsigned)HO_) && ((unsigned)(c + dx) < (unsigned)WO_);
            float v = valid ? lgp[cl][h * 9 + jj] : sm0[h];
            gv[jj] = v; s += v;
        }
        float* gp = gbuf + (((size_t)(b * 4 + h) << 10) + cy * 32 + c) * 9;
        #pragma unroll
        for (int jj = 0; jj < 9; ++jj) { gp[jj] = gv[jj]; lgp[cl][h * 9 + jj] = gv[jj]; }
        hsum[cl][h] = s;
    }
    __syncthreads();
    if (tid < 16) {
        float dd = 4.f * (hsum[tid][0] + hsum[tid][1] + hsum[tid][2] + hsum[tid][3]) + ATT_EPS;
        den[tid] = 1.f / dd;
        denb[b * NOUT + cy * 32 + cx0 + tid] = dd;
    }
    __syncthreads();
    if (tid < 64) {
        int cl = tid >> 2, h = tid & 3;
        float inv = den[cl];
        #pragma unroll
        for (int jj = 0; jj < 9; ++jj) lgp[cl][h * 9 + jj] *= inv;
    }
    __syncthreads();

    // ---- AV update: v rows DIRECT from global; 16 threads/position ----
    {
        int cl = tid >> 4, d0 = (tid & 15) << 3;
        int c = cx0 + cl;
        int rx0 = min(max(c - 1, 0), WO_ - 3);
        float acc[8] = {};
        #pragma unroll
        for (int h = 0; h < 4; ++h)
            #pragma unroll
            for (int jj = 0; jj < 9; ++jj) {
                float cf = lgp[cl][h * 9 + jj];
                int ky = jj / 3, kx = jj - ky * 3;
                const ushort* vp = vbuf + (((size_t)(b * 4 + h) << 10) + (ry0 + ky) * 32 + rx0 + kx) * DD + d0;
                uint4 v0 = *(const uint4*)(vp);
                const ushort* vs0 = (const ushort*)&v0;
                #pragma unroll
                for (int t = 0; t < 8; ++t) acc[t] += cf * bf2f(vs0[t]);
            }
        #pragma unroll
        for (int t = 0; t < 8; t += 4) {
            float4 o = *(float4*)&xsf[cl][d0 + t];
            o.x += acc[t]; o.y += acc[t + 1]; o.z += acc[t + 2]; o.w += acc[t + 3];
            *(float4*)&xsf[cl][d0 + t] = o;
        }
    }
    __syncthreads();

    // ---- P3: FFN1 (gelu) — A = bf16(xsf rows 0..15) into Aq ----
    for (int l = tid; l < 512; l += 256) {
        int r = l >> 5, c4 = (l & 31) << 2;
        ushort4 o;
        o.x = f2bf(xsf[r][c4 + 0]); o.y = f2bf(xsf[r][c4 + 1]);
        o.z = f2bf(xsf[r][c4 + 2]); o.w = f2bf(xsf[r][c4 + 3]);
        *(ushort4*)&Aq[r][c4] = o;
    }
    __syncthreads();
    {
        const int wn = wid * 64;
        f32x4 acc[4] = {};
        #pragma unroll
        for (int ks = 0; ks < 4; ++ks) {
            int kk = ks * 32 + lk;
            bf16x8 a0 = *(const bf16x8*)&Aq[lr][kk];
            #pragma unroll
            for (int ni = 0; ni < 4; ++ni) {
                bf16x8 bF = *(const bf16x8*)(w1b + (size_t)(wn + ni * 16 + lr) * DD + kk);
                acc[ni] = __builtin_amdgcn_mfma_f32_16x16x32_bf16(a0, bF, acc[ni], 0, 0, 0);
            }
        }
        #pragma unroll
        for (int ni = 0; ni < 4; ++ni) {
            int n = wn + ni * 16 + (lane & 15);
            float bv = b1[n];
            #pragma unroll
            for (int r = 0; r < 4; ++r) {
                int m = ((lane >> 4) << 2) + r;
                float v = acc[ni][r] + bv;
                v = 0.5f * v * (1.f + erff(v * 0.70710678118654752f));
                h1s[m][n] = f2bf(v);
            }
        }
    }
    __syncthreads();

    // ---- P4: FFN2 -> es ----
    {
        const int wn = wid * 32;
        f32x4 acc[2] = {};
        #pragma unroll
        for (int ks = 0; ks < 8; ++ks) {
            int kk = ks * 32 + lk;
            bf16x8 a0 = *(const bf16x8*)&h1s[lr][kk];
            #pragma unroll
            for (int ni = 0; ni < 2; ++ni) {
                bf16x8 bF = *(const bf16x8*)(w2b + (size_t)(wn + ni * 16 + lr) * 256 + kk);
                acc[ni] = __builtin_amdgcn_mfma_f32_16x16x32_bf16(a0, bF, acc[ni], 0, 0, 0);
            }
        }
        #pragma unroll
        for (int ni = 0; ni < 2; ++ni) {
            int n = wn + ni * 16 + (lane & 15);
            float bv = b2[n];
            #pragma unroll
            for (int r = 0; r < 4; ++r)
                es[((lane >> 4) << 2) + r][n] = acc[ni][r] + bv;
        }
    }
    __syncthreads();
    if (tid < 128) {   // LN stats: 8 threads/row, 16 rows
        int r = tid >> 3, qq = tid & 7;
        float s = 0.f, s2 = 0.f;
        #pragma unroll
        for (int c = 0; c < 16; ++c) { float v = es[r][qq * 16 + c]; s += v; s2 += v * v; }
        s += __shfl_down(s, 1, 64); s2 += __shfl_down(s2, 1, 64);
        s += __shfl_down(s, 2, 64); s2 += __shfl_down(s2, 2, 64);
        s += __shfl_down(s, 4, 64); s2 += __shfl_down(s2, 4, 64);
        if (qq == 0) {
            float mu = s * (1.f / DD);
            float var = s2 * (1.f / DD) - mu * mu;
            rstat[r][0] = mu; rstat[r][1] = rsqrtf(var + LN_EPS);
        }
    }
    __syncthreads();
    // ---- final: xout = xsf + LN(es); also d_out on LAST ----
    for (int l = tid; l < 512; l += 256) {
        int r = l >> 5, c4 = (l & 31) << 2;
        float mu = rstat[r][0], rs = rstat[r][1];
        size_t off = ((size_t)(b * NOUT + cy * 32 + cx0 + r)) * DD + c4;
        float4 o;
        o.x = xsf[r][c4 + 0] + (es[r][c4 + 0] - mu) * rs * lg_[c4 + 0] + lb_[c4 + 0];
        o.y = xsf[r][c4 + 1] + (es[r][c4 + 1] - mu) * rs * lg_[c4 + 1] + lb_[c4 + 1];
        o.z = xsf[r][c4 + 2] + (es[r][c4 + 2] - mu) * rs * lg_[c4 + 2] + lb_[c4 + 2];
        o.w = xsf[r][c4 + 3] + (es[r][c4 + 3] - mu) * rs * lg_[c4 + 3] + lb_[c4 + 3];
        *(float4*)(xout + off) = o;
        if (LAST) *(float4*)(out + off) = o;
    }
}

// ---------------------------------------------------------------------------
// A_row (blocks 0..32767) and A_col incl. dump (blocks 32768..65535).
// ---------------------------------------------------------------------------
__global__ __launch_bounds__(256)
void arowcol_kernel(const float* __restrict__ gbuf, const float* __restrict__ denb,
                    float* __restrict__ Arow, float* __restrict__ Acol)
{
    const int tid = threadIdx.x;
    __shared__ int   cols[9];
    __shared__ float vals[9];
    __shared__ float wred[9][4];
    if (blockIdx.x < 32768) {
        const int bi = blockIdx.x;
        const int b = bi >> 12, i = bi & 4095;
        const int h = i >> 10, p = i & 1023;
        const int cy = p >> 5, cx = p & 31;
        if (tid < 9) {
            int dy = tid / 3 - 1, dx = tid % 3 - 1;
            bool valid = ((unsigned)(cy + dy) < (unsigned)HO_) && ((unsigned)(cx + dx) < (unsigned)WO_);
            cols[tid] = valid ? (cy + dy) * WO_ + (cx + dx) : 0;
            vals[tid] = 4.f * gbuf[(((size_t)(b * 4 + h) << 10) + p) * 9 + tid];
        }
        __syncthreads();
        float* row = Arow + (size_t)bi * NOUT;
        #pragma unroll
        for (int cc = 0; cc < 4; ++cc) {
            int c = cc * 256 + tid;
            float acc = 0.f;
            #pragma unroll
            for (int jj = 0; jj < 9; ++jj)
                if (cols[jj] == c) acc += vals[jj];
            row[c] = acc;
        }
    } else {
        const int br = blockIdx.x - 32768;
        const int b = br >> 12, r = br & 4095;
        const int h = r & 3, coarse = r >> 2;
        const int cy = coarse >> 5, cx = coarse & 31;
        if (tid < 9) {
            int dy = tid / 3 - 1, dx = tid % 3 - 1;
            int py = cy - dy, px = cx - dx;
            float v = 0.f;
            if ((unsigned)py < (unsigned)HO_ && (unsigned)px < (unsigned)WO_) {
                int p = py * WO_ + px;
                v = gbuf[(((size_t)(b * 4 + h) << 10) + p) * 9 + tid] / denb[b * NOUT + p];
            }
            vals[tid] = v;
        }
        if (r == 0) {
            float part[9] = {};
            for (int p = tid; p < NOUT; p += 256) {
                float invd = 1.f / denb[b * NOUT + p];
                int py = p >> 5, px = p & 31;
                #pragma unroll
                for (int jj = 0; jj < 9; ++jj) {
                    int dy = jj / 3 - 1, dx = jj % 3 - 1;
                    bool valid = ((unsigned)(py + dy) < (unsigned)HO_) && ((unsigned)(px + dx) < (unsigned)WO_);
                    if (!valid) part[jj] += invd;
                }
            }
            #pragma unroll
            for (int jj = 0; jj < 9; ++jj) {
                float s = part[jj];
                #pragma unroll
                for (int o = 32; o > 0; o >>= 1) s += __shfl_down(s, o, 64);
                if ((tid & 63) == 0) wred[jj][tid >> 6] = s;
            }
            __syncthreads();
            if (tid < 9) {
                float s = wred[tid][0] + wred[tid][1] + wred[tid][2] + wred[tid][3];
                float H = 0.f;
                for (int h2 = 0; h2 < 4; ++h2)
                    H += gbuf[(((size_t)(b * 4 + h2)) << 10) * 9];
                vals[tid] += H * s;
            }
        }
        __syncthreads();
        float* row = Acol + (size_t)br * NOUT;
        #pragma unroll
        for (int cc = 0; cc < 4; ++cc) {
            int c = cc * 256 + tid;
            row[c] = (c < 36) ? vals[c % 9] : 0.f;
        }
    }
}

// ---------------------------------------------------------------------------
extern "C" void kernel_launch(void* const* d_in, const int* in_sizes, int n_in,
                              void* d_out, int out_size, void* d_ws, size_t ws_size,
                              hipStream_t stream)
{
    const float* x        = (const float*)d_in[0];
    const float* seed_w   = (const float*)d_in[1];
    const float* wq       = (const float*)d_in[2];
    const float* wk       = (const float*)d_in[3];
    const float* wv       = (const float*)d_in[4];
    const float* w1       = (const float*)d_in[5];
    const float* b1       = (const float*)d_in[6];
    const float* w2       = (const float*)d_in[7];
    const float* b2       = (const float*)d_in[8];
    const float* ln_in_g  = (const float*)d_in[9];
    const float* ln_in_b  = (const float*)d_in[10];
    const float* ln_out_g = (const float*)d_in[11];
    const float* ln_out_b = (const float*)d_in[12];
    const float* rpb      = (const float*)d_in[13];
    const float* tau      = (const float*)d_in[14];

    float* out  = (float*)d_out;
    float* Arow = out + (size_t)BB * NOUT * DD;
    float* Acol = Arow + (size_t)BB * NIN * NOUT;

    // Must-survive scratch in d_ws:
    float* ws    = (float*)d_ws;
    float* xout  = ws;                                 // 1,048,576
    float* gbuf  = xout + (size_t)BB * NOUT * DD;      // 294,912
    float* denb  = gbuf + (size_t)BB * 4 * NOUT * 9;   // 8,192
    ushort* wb   = (ushort*)(denb + BB * NOUT);        // 262,144 ushorts
    ushort* wkb  = wb;
    ushort* wvb  = wb + 16384;
    ushort* wqb  = wb + 32768;
    ushort* w1b  = wb + 49152;
    ushort* w2b  = wb + 81920;
    ushort* wcb  = wb + 114688;

    // Dead-by-the-end scratch carved from the A_row output region:
    ushort* kbuf = (ushort*)Arow;                       // 4,194,304 ushorts
    ushort* vbuf = kbuf + (size_t)4194304;              // 4,194,304 ushorts

    // --- preamble: weight convert, then merged prep_kv + conv_ln ---
    wconvert_kernel<<<1024, 256, 0, stream>>>(wq, wk, wv, w1, w2, seed_w, wb);
    prep_kernel<<<640, 256, 0, stream>>>(x, wkb, wvb, wcb, ln_in_g, ln_in_b,
                                         ln_out_g, ln_out_b, kbuf, vbuf, xout);

    // --- 3 fully fused iterations (512 blocks each) ---
    for (int it = 0; it < 3; ++it) {
        if (it < 2)
            iter_kernel<0><<<BB * HO_ * 2, 256, 0, stream>>>(
                xout, kbuf, vbuf, wqb, w1b, w2b, b1, b2, ln_out_g, ln_out_b,
                rpb, tau, gbuf, denb, out);
        else
            iter_kernel<1><<<BB * HO_ * 2, 256, 0, stream>>>(
                xout, kbuf, vbuf, wqb, w1b, w2b, b1, b2, ln_out_g, ln_out_b,
                rpb, tau, gbuf, denb, out);
    }

    // --- epilogue: A_row + A_col (+dump inline) ---
    arowcol_kernel<<<2 * BB * NIN, 256, 0, stream>>>(gbuf, denb, Arow, Acol);
}